// Round 9
// baseline (732.267 us; speedup 1.0000x reference)
//
#include <hip/hip_runtime.h>

#define BB 2
#define NN 20000
#define HH 128
#define EE 200000
#define TILE 32      // dst nodes per block
#define NTIL 625     // NN/TILE exact
#define NBLK 79      // ceil(NN/256)

typedef unsigned short u16;
typedef __attribute__((ext_vector_type(4))) float f32x4;
typedef __bf16 bf16x8 __attribute__((ext_vector_type(8)));

#define MFMA(a, b, c) __builtin_amdgcn_mfma_f32_16x16x32_bf16((a), (b), (c), 0, 0, 0)

__device__ __forceinline__ float bf2f(u16 u) {
    union { unsigned int i; float f; } v; v.i = ((unsigned int)u) << 16; return v.f;
}
__device__ __forceinline__ u16 f2bf(float f) {
    union { __bf16 h; u16 u; } v; v.h = (__bf16)f; return v.u;
}
#if __has_builtin(__builtin_amdgcn_rcpf)
__device__ __forceinline__ float rcpf(float x) { return __builtin_amdgcn_rcpf(x); }
#else
__device__ __forceinline__ float rcpf(float x) { return 1.f / x; }
#endif
__device__ __forceinline__ float silu_f(float z) { return z * rcpf(1.f + __expf(-z)); }
// flag-routed load (setup kernels only): f32 raw or bf16 raw
__device__ __forceinline__ float ldv(const void* p, long i, int f) {
    return f ? ((const float*)p)[i] : bf2f(((const u16*)p)[i]);
}

// ---------------- launch 1: dtype detection + cnt zeroing ----------------
__global__ __launch_bounds__(256) void detect_zero_kernel(const u16* __restrict__ f,
                                                          int* __restrict__ flag,
                                                          int* __restrict__ cnt) {
    int i = blockIdx.x * 256 + threadIdx.x;
    if (i < 40000) cnt[i] = 0;            // cnt_up | cnt_dn contiguous
    if (blockIdx.x == 0) {
        int tid = threadIdx.x;
        u16 v = f[tid * 2];
        int e = (v >> 7) & 0xFF;
        int ok = (e >= 101 && e <= 143) ? 1 : 0;
        __shared__ int c;
        if (tid == 0) c = 0;
        __syncthreads();
        atomicAdd(&c, ok);
        __syncthreads();
        if (tid == 0) *flag = (c < 200) ? 1 : 0;   // 1 => inputs are float32
    }
}

// ---------------- launch 2: fused setup (canon | frags | edge counts) ----------------
#define C5TOT 5281540
#define FTOT 180224
#define S1 C5TOT
#define S2 (S1 + FTOT)
#define S3 (S2 + 2 * EE)
struct P18 { const void* p[18]; };
struct P8 { const void* w[8]; };

__global__ __launch_bounds__(256) void setup_kernel(
    P18 cp, P8 wf, const int* __restrict__ eu, const int* __restrict__ ed,
    u16* __restrict__ canon, u16* __restrict__ fbase,
    int* __restrict__ cnt_up, int* __restrict__ cnt_dn, const int* __restrict__ flag)
{
    long i = (long)blockIdx.x * 256 + threadIdx.x;
    if (i < S1) {
        static const int off[19] = {
            0, 5120000, 5240000, 5260000, 5280000,
            5280128, 5280256, 5280384, 5280512, 5280640,
            5280642, 5280770, 5280898, 5281026, 5281154, 5281282,
            5281284, 5281412, 5281540 };
        static const int rsz[18] = {
            5120000, 120000, 20000, 20000,
            128, 128, 128, 128, 128, 1,
            128, 128, 128, 128, 128, 1,
            128, 128 };
        static const int soff[18] = {
            0, 0, 0, 0,
            32768, 0, 0, 0, 0, 0,
            32768, 0, 0, 0, 0, 0,
            0, 0 };
        int j = (int)i;
        int isf = *flag;
        int t = 0;
#pragma unroll 1
        while (j >= off[t + 1]) ++t;
        int k = j - off[t];
        u16 v = 0;
        if (k < rsz[t]) v = f2bf(ldv(cp.p[t], (long)soff[t] + k, isf));
        canon[j] = v;
        return;
    }
    if (i < S2) {
        static const int foff[9] = { 0, 32768, 49152, 65536, 98304, 114688,
                                     131072, 163840, 180224 };
        int j = (int)(i - S1);
        int isf = *flag;
        int t = 0;
#pragma unroll 1
        while (j >= foff[t + 1]) ++t;
        int m = j - foff[t];
        int jj = m & 7, lane = (m >> 3) & 63, nt = (m >> 9) & 7, kt = m >> 12;
        int k = kt * 32 + ((lane >> 4) * 8) + jj;
        int n = nt * 16 + (lane & 15);
        fbase[j] = f2bf(ldv(wf.w[t], (long)k * 128 + n, isf));
        return;
    }
    if (i < S3) {
        int e = (int)(i - S2);
        if (e < EE) atomicAdd(&cnt_up[eu[EE + e]], 1);
        else atomicAdd(&cnt_dn[ed[EE + e - EE]], 1);
    }
}

// ---------------- launch 2b: W2@P1 fusion precompute ----------------
__global__ __launch_bounds__(256) void gemm_fuse_kernel(
    const void* __restrict__ w2u, const void* __restrict__ p1u,
    const void* __restrict__ b2u, const void* __restrict__ bp1u,
    const void* __restrict__ w2d, const void* __restrict__ p1d,
    const void* __restrict__ b2d, const void* __restrict__ bp1d,
    u16* __restrict__ fragu, u16* __restrict__ fragd,
    u16* __restrict__ cbp1u, u16* __restrict__ cbp1d,
    const int* __restrict__ flag)
{
    const int dir = blockIdx.x >> 6;                 // 64 blocks per direction
    const int idx = (blockIdx.x & 63) * 256 + threadIdx.x;   // 0..16383
    const int k = idx >> 7, n = idx & 127;
    const int isf = *flag;
    const void* W2 = dir ? w2d : w2u;
    const void* P1 = dir ? p1d : p1u;
    float s = 0.f;
#pragma unroll 4
    for (int m = 0; m < 128; ++m)
        s += ldv(W2, (long)k * 128 + m, isf) * ldv(P1, (long)m * 128 + n, isf);
    u16* dst = dir ? fragd : fragu;
    dst[(((k >> 5) * 8 + (n >> 4)) * 64 + ((k >> 3) & 3) * 16 + (n & 15)) * 8 + (k & 7)] = f2bf(s);
    if (idx < 128) {
        const void* B2 = dir ? b2d : b2u;
        const void* BP1 = dir ? bp1d : bp1u;
        float t = 0.f;
#pragma unroll 4
        for (int m = 0; m < 128; ++m)
            t += ldv(B2, m, isf) * ldv(P1, (long)m * 128 + idx, isf);
        (dir ? cbp1d : cbp1u)[idx] = f2bf(t + ldv(BP1, idx, isf));
    }
}

// ---------------- CSR scans + scatter ----------------
struct SP { const int* cnt[2]; int* cur[2]; int* bsum[2]; };

__global__ __launch_bounds__(256) void scan1_kernel(SP p) {
    int half = blockIdx.x / NBLK;
    int b = blockIdx.x - half * NBLK;
    int t = threadIdx.x;
    int i = b * 256 + t;
    __shared__ int buf[256];
    int v = (i < NN) ? p.cnt[half][i] : 0;
    buf[t] = v;
    __syncthreads();
    for (int s = 1; s < 256; s <<= 1) {
        int x = (t >= s) ? buf[t - s] : 0;
        __syncthreads();
        buf[t] += x;
        __syncthreads();
    }
    if (i < NN) p.cur[half][i] = buf[t] - v;   // exclusive within block
    if (t == 255) p.bsum[half][b] = buf[255];
}

__global__ __launch_bounds__(256) void scan2_kernel(int* __restrict__ bu, int* __restrict__ bd) {
    __shared__ int buf[2][128];
    int half = threadIdx.x >> 7, t = threadIdx.x & 127;
    int* bs = half ? bd : bu;
    int v = (t < NBLK) ? bs[t] : 0;
    buf[half][t] = v;
    __syncthreads();
    for (int s = 1; s < 128; s <<= 1) {
        int x = (t >= s) ? buf[half][t - s] : 0;
        __syncthreads();
        buf[half][t] += x;
        __syncthreads();
    }
    if (t < NBLK) bs[t] = buf[half][t] - v;    // exclusive block offsets
}

__global__ void scatter2_kernel(const int* __restrict__ eu, const int* __restrict__ ed,
                                int* __restrict__ cu, const int* __restrict__ bu,
                                int* __restrict__ cd, const int* __restrict__ bd,
                                int* __restrict__ su, int* __restrict__ sd) {
    int e = blockIdx.x * 256 + threadIdx.x;
    if (e < EE) {
        int d = eu[EE + e];
        int p = atomicAdd(&cu[d], 1) + bu[d >> 8];
        su[p] = e;
    } else {
        e -= EE;
        if (e < EE) {
            int d = ed[EE + e];
            int p = atomicAdd(&cd[d], 1) + bd[d >> 8];
            sd[p] = e;
        }
    }
}

// ---------------- edge kernel: dst-tile ownership, ZERO global atomics ----------------
// Each block owns 32 dst nodes of one batch. It walks that tile's CSR-contiguous
// edge ranges (both directions) in 64-row chunks through the MFMA pipeline,
// accumulates msg into a 32x128 f32 LDS accumulator (ds_add_f32) and pos into
// 32x3, then plain-stores msg as bf16 and pos as f32. No ws zeroing needed.
// Offsets from CSR arrays: off(d) = bsum[d>>8] + cur[d] - cnt[d] (cur = excl+cnt
// after scatter2).
struct EP2 {
    const int* eidx; const int* es; const u16* deg;
    const int* cnt; const int* cur; const int* bsum;
    const u16* fW1; const u16* fW2;
    const u16* w1last; const u16* bias1; const u16* bias2;
    const u16* biasp1; const u16* wp2; const u16* biasp2;
};

__global__ __launch_bounds__(512, 2) void edge_kernel(
    const u16* __restrict__ feat, const u16* __restrict__ posit,   // canonical bf16
    EP2 up, EP2 dn,
    u16* __restrict__ msg_out, float* __restrict__ pos_out)
{
    const int tid = threadIdx.x;
    const int lane = tid & 63;
    const int wv = tid >> 6;
    const int bb = blockIdx.x / NTIL;
    const int tile = blockIdx.x - bb * NTIL;
    const int n0 = tile * TILE;

    __shared__ u16 sA[64][136];    // h_src -> messages
    __shared__ u16 sB[64][136];    // h_dst -> pos-hidden
    __shared__ u16 sC[64][136];    // L1 hidden | pad 128..135 = {dist,dx,dy,dz}
    __shared__ float accM[TILE][132];
    __shared__ float accP[TILE][4];
    __shared__ float sInv[64];
    __shared__ int sDloc[64];

    for (int i = tid; i < TILE * 132; i += 512) ((float*)accM)[i] = 0.f;
    if (tid < TILE * 4) ((float*)accP)[tid] = 0.f;
    __syncthreads();   // acc init visible (also covers zero-edge tiles)

    const int wm = wv >> 2;        // 0..1 : 32-row half of chunk
    const int wn = wv & 3;         // 0..3 : column quarter
    const int rbase = wm * 32;
    const int mrow = lane & 15;
    const int kq = (lane >> 4) * 8;
    const int crow = (lane >> 4) * 4;
    const int ccol = lane & 15;

#pragma unroll 1
    for (int dir = 0; dir < 2; ++dir) {
        const EP2 P = dir ? dn : up;
        const int e0 = P.bsum[n0 >> 8] + P.cur[n0] - P.cnt[n0];
        const int n1 = n0 + TILE;
        const int e1 = (n1 >= NN) ? EE : (P.bsum[n1 >> 8] + P.cur[n1] - P.cnt[n1]);

#pragma unroll 1
        for (int c0 = e0; c0 < e1; c0 += 64) {
            // gather + meta (8 threads/row, 32B each; part 0 also does meta)
            {
                const int r = tid >> 3, part = tid & 7;
                int slot = c0 + r; if (slot >= e1) slot = e1 - 1;   // replicate last
                int e = P.es[slot];
                int s = P.eidx[e];
                int d = P.eidx[EE + e];
                if (part == 0) {
                    sDloc[r] = d - n0;
                    sInv[r] = 1.f / fmaxf(bf2f(P.deg[d]), 1.f);
                    const u16* ps = posit + ((size_t)bb * NN + s) * 3;
                    const u16* pd = posit + ((size_t)bb * NN + d) * 3;
                    float dx = bf2f(ps[0]) - bf2f(pd[0]);
                    float dy = bf2f(ps[1]) - bf2f(pd[1]);
                    float dz = bf2f(ps[2]) - bf2f(pd[2]);
                    *(float4*)&sC[r][128] =
                        make_float4(sqrtf(dx * dx + dy * dy + dz * dz), dx, dy, dz);
                }
                const uint4* fs = (const uint4*)(feat + ((size_t)bb * NN + s) * HH);
                const uint4* fd = (const uint4*)(feat + ((size_t)bb * NN + d) * HH);
                uint4* as = (uint4*)&sA[r][part * 16];
                uint4* ad = (uint4*)&sB[r][part * 16];
                as[0] = fs[part * 2];     as[1] = fs[part * 2 + 1];
                ad[0] = fd[part * 2];     ad[1] = fd[part * 2 + 1];
            }
            __syncthreads();   // B1

            // ----- msg layer 1 : [h_src | h_dst] @ W1  (K=256, 2mt x 2nt/wave) -----
            f32x4 acc[2][2];
#pragma unroll
            for (int mt = 0; mt < 2; ++mt) {
                acc[mt][0] = (f32x4){0.f, 0.f, 0.f, 0.f};
                acc[mt][1] = (f32x4){0.f, 0.f, 0.f, 0.f};
            }
#pragma unroll
            for (int kt = 0; kt < 8; ++kt) {
                const u16* Xb = (kt < 4) ? &sA[0][0] : &sB[0][0];
                const int kk = (kt & 3) * 32 + kq;
                bf16x8 bw0 = *(const bf16x8*)(P.fW1 + (size_t)(((kt * 8 + wn * 2) * 64 + lane) * 8));
                bf16x8 bw1 = *(const bf16x8*)(P.fW1 + (size_t)(((kt * 8 + wn * 2 + 1) * 64 + lane) * 8));
#pragma unroll
                for (int mt = 0; mt < 2; ++mt) {
                    bf16x8 a = *(const bf16x8*)(Xb + (rbase + mt * 16 + mrow) * 136 + kk);
                    acc[mt][0] = MFMA(a, bw0, acc[mt][0]);
                    acc[mt][1] = MFMA(a, bw1, acc[mt][1]);
                }
            }

            // L1 epilogue: + dist*W1[256] + b1, silu -> sC
#pragma unroll
            for (int n2 = 0; n2 < 2; ++n2) {
                const int col = (wn * 2 + n2) * 16 + ccol;
                const float wl = bf2f(P.w1last[col]);
                const float bb1 = bf2f(P.bias1[col]);
#pragma unroll
                for (int mt = 0; mt < 2; ++mt) {
#pragma unroll
                    for (int r = 0; r < 4; ++r) {
                        const int row = rbase + mt * 16 + crow + r;
                        const float dist = ((const float*)&sC[row][128])[0];
                        float z = fmaf(dist, wl, acc[mt][n2][r]) + bb1;
                        sC[row][col] = f2bf(silu_f(z));
                    }
                }
            }
            __syncthreads();   // B2: L1 hidden visible; sA/sB reads done

            // ----- fused pass : sC @ [W2 | W2@P1]  (K=128, 2mt x 4nt/wave) -----
            f32x4 facc[2][4];
#pragma unroll
            for (int mt = 0; mt < 2; ++mt)
#pragma unroll
                for (int j = 0; j < 4; ++j) facc[mt][j] = (f32x4){0.f, 0.f, 0.f, 0.f};
            const int nt0 = wn * 4;
#pragma unroll
            for (int kt = 0; kt < 4; ++kt) {
                const int kk = kt * 32 + kq;
                bf16x8 bw[4];
#pragma unroll
                for (int j = 0; j < 4; ++j) {
                    const int nt = nt0 + j;
                    const size_t off = (nt & 8)
                        ? (size_t)(16384 + ((kt * 8 + (nt & 7)) * 64 + lane) * 8)
                        : (size_t)(((kt * 8 + nt) * 64 + lane) * 8);
                    bw[j] = *(const bf16x8*)(P.fW2 + off);
                }
#pragma unroll
                for (int mt = 0; mt < 2; ++mt) {
                    bf16x8 a = *(const bf16x8*)(&sC[0][0] + (rbase + mt * 16 + mrow) * 136 + kk);
#pragma unroll
                    for (int j = 0; j < 4; ++j) facc[mt][j] = MFMA(a, bw[j], facc[mt][j]);
                }
            }

            // fused epilogue: wn<2 -> messages (sA); wn>=2 -> pos-hidden (sB)
            if (wn < 2) {
#pragma unroll
                for (int j = 0; j < 4; ++j) {
                    const int col = (nt0 + j) * 16 + ccol;
                    const float b2v = bf2f(P.bias2[col]);
#pragma unroll
                    for (int mt = 0; mt < 2; ++mt) {
#pragma unroll
                        for (int r = 0; r < 4; ++r) {
                            const int row = rbase + mt * 16 + crow + r;
                            sA[row][col] = f2bf(facc[mt][j][r] + b2v);
                        }
                    }
                }
            } else {
#pragma unroll
                for (int j = 0; j < 4; ++j) {
                    const int col = (nt0 - 8 + j) * 16 + ccol;
                    const float fbv = bf2f(P.biasp1[col]);   // fused bias b2@P1 + bp1
#pragma unroll
                    for (int mt = 0; mt < 2; ++mt) {
#pragma unroll
                        for (int r = 0; r < 4; ++r) {
                            const int row = rbase + mt * 16 + crow + r;
                            sB[row][col] = f2bf(silu_f(facc[mt][j][r] + fbv));
                        }
                    }
                }
            }
            __syncthreads();   // B3: messages + pos-hidden visible

            // msg accumulation into accM (LDS atomics; rows sorted by dst)
            {
                const int scol = tid & 127;
                const int r0 = (tid >> 7) * 16;
                float vals[16];
#pragma unroll
                for (int j = 0; j < 16; ++j) vals[j] = bf2f(sA[r0 + j][scol]);
                float accv = 0.f;
                int dprev = sDloc[r0];
                float invprev = sInv[r0];
#pragma unroll
                for (int j = 0; j < 16; ++j) {
                    const int r = r0 + j;
                    int dcur = sDloc[r];
                    if (dcur != dprev) {
                        atomicAdd(&accM[dprev][scol], accv * invprev);
                        accv = 0.f; dprev = dcur; invprev = sInv[r];
                    }
                    accv += (c0 + r < e1) ? vals[j] : 0.f;
                }
                atomicAdd(&accM[dprev][scol], accv * invprev);
            }

            // pos layer 2 : tanh(hidden @ p2 + bp2) ; accumulate wgt*rel into accP
            {
                const int r = tid >> 2, q = tid & 3;   // 4 threads/row, 32 cols each
                if (r < 64) {
                    const unsigned* t32 = (const unsigned*)&sB[r][q * 32];
                    const unsigned* w32 = (const unsigned*)(P.wp2 + q * 32);
                    float p = 0.f;
#pragma unroll
                    for (int k = 0; k < 16; ++k) {
                        unsigned a = t32[k], b = w32[k];
                        union { unsigned i; float f; } al, ah, bl, bh;
                        al.i = a << 16; ah.i = a & 0xffff0000u;
                        bl.i = b << 16; bh.i = b & 0xffff0000u;
                        p = fmaf(al.f, bl.f, p);
                        p = fmaf(ah.f, bh.f, p);
                    }
                    p += __shfl_xor(p, 1);
                    p += __shfl_xor(p, 2);
                    if (q == 0 && c0 + r < e1) {
                        float wgt = tanhf(p + bf2f(P.biasp2[0]));
                        const float* rp = (const float*)&sC[r][128];   // {dist,dx,dy,dz}
                        const int dl = sDloc[r];
                        atomicAdd(&accP[dl][0], wgt * rp[1]);
                        atomicAdd(&accP[dl][1], wgt * rp[2]);
                        atomicAdd(&accP[dl][2], wgt * rp[3]);
                    }
                }
            }
            __syncthreads();   // B4: acc done; sA/sB/sC reusable next chunk
        }
    }

    __syncthreads();   // ensure all acc visible for store

    // store msg: 32 rows x 128 cols bf16 (plain coalesced stores)
    {
        const int r = tid >> 4, c = (tid & 15) * 8;
        uint4 o;
        o.x = (unsigned)f2bf(accM[r][c + 0]) | ((unsigned)f2bf(accM[r][c + 1]) << 16);
        o.y = (unsigned)f2bf(accM[r][c + 2]) | ((unsigned)f2bf(accM[r][c + 3]) << 16);
        o.z = (unsigned)f2bf(accM[r][c + 4]) | ((unsigned)f2bf(accM[r][c + 5]) << 16);
        o.w = (unsigned)f2bf(accM[r][c + 6]) | ((unsigned)f2bf(accM[r][c + 7]) << 16);
        *(uint4*)&msg_out[((size_t)bb * NN + n0 + r) * HH + c] = o;
    }
    if (tid < TILE * 3) {
        const int r = tid / 3, comp = tid - r * 3;
        pos_out[((size_t)bb * NN + n0 + r) * 3 + comp] = accP[r][comp];
    }
}

// ---------------- update + fused pos output ----------------
__global__ __launch_bounds__(256) void update_kernel(
    const void* __restrict__ rawfeat, const void* __restrict__ rawpos,
    const u16* __restrict__ fU1, const u16* __restrict__ bu1,
    const u16* __restrict__ fU2, const u16* __restrict__ bu2,
    void* __restrict__ outp, const u16* __restrict__ magg, const float* __restrict__ pacc,
    const int* __restrict__ flag)
{
    const int tid = threadIdx.x;
    const int lane = tid & 63;
    const int wv = tid >> 6;
    const int row0 = blockIdx.x * 64;
    const int isf = *flag;

    __shared__ u16 sA[64][136];   // features (bf16)
    __shared__ u16 sB[64][136];   // msg_acc -> hidden (reused)

    if (isf) {
        const float* fp = (const float*)rawfeat + (size_t)row0 * HH;
        for (int i = tid; i < 1024; i += 256) {
            int r = i >> 4, c = (i & 15) * 8;
            float4 v0 = *(const float4*)(fp + (size_t)r * HH + c);
            float4 v1 = *(const float4*)(fp + (size_t)r * HH + c + 4);
            uint4 o;
            o.x = (unsigned)f2bf(v0.x) | ((unsigned)f2bf(v0.y) << 16);
            o.y = (unsigned)f2bf(v0.z) | ((unsigned)f2bf(v0.w) << 16);
            o.z = (unsigned)f2bf(v1.x) | ((unsigned)f2bf(v1.y) << 16);
            o.w = (unsigned)f2bf(v1.z) | ((unsigned)f2bf(v1.w) << 16);
            *(uint4*)&sA[r][c] = o;
        }
    } else {
        const uint4* fp = (const uint4*)((const u16*)rawfeat + (size_t)row0 * HH);
        for (int i = tid; i < 1024; i += 256) {
            int r = i >> 4, c = i & 15;
            *(uint4*)&sA[r][c * 8] = fp[i];
        }
    }
    {
        // msg is already bf16: straight copy
        const uint4* am = (const uint4*)magg + (size_t)row0 * 16;
        for (int i = tid; i < 1024; i += 256) {
            int r = i >> 4, c = i & 15;
            *(uint4*)&sB[r][c * 8] = am[i];
        }
    }
    __syncthreads();

    const int nt0 = wv * 2;
    const int mrow = lane & 15;
    const int kq = (lane >> 4) * 8;
    const int crow = (lane >> 4) * 4;
    const int ccol = lane & 15;

    f32x4 acc[4][2];
#pragma unroll
    for (int mt = 0; mt < 4; ++mt) {
        acc[mt][0] = (f32x4){0.f, 0.f, 0.f, 0.f};
        acc[mt][1] = (f32x4){0.f, 0.f, 0.f, 0.f};
    }
#pragma unroll
    for (int kt = 0; kt < 8; ++kt) {
        const u16* Xb = (kt < 4) ? &sA[0][0] : &sB[0][0];
        const int kk = (kt & 3) * 32 + kq;
        bf16x8 bw0 = *(const bf16x8*)(fU1 + (size_t)(((kt * 8 + nt0) * 64 + lane) * 8));
        bf16x8 bw1 = *(const bf16x8*)(fU1 + (size_t)(((kt * 8 + nt0 + 1) * 64 + lane) * 8));
#pragma unroll
        for (int mt = 0; mt < 4; ++mt) {
            bf16x8 a = *(const bf16x8*)(Xb + (mt * 16 + mrow) * 136 + kk);
            acc[mt][0] = MFMA(a, bw0, acc[mt][0]);
            acc[mt][1] = MFMA(a, bw1, acc[mt][1]);
        }
    }
    __syncthreads();

#pragma unroll
    for (int mt = 0; mt < 4; ++mt) {
#pragma unroll
        for (int n2 = 0; n2 < 2; ++n2) {
            const int col = (nt0 + n2) * 16 + ccol;
            const float bb = bf2f(bu1[col]);
#pragma unroll
            for (int r = 0; r < 4; ++r) {
                const int row = mt * 16 + crow + r;
                sB[row][col] = f2bf(silu_f(acc[mt][n2][r] + bb));
            }
        }
    }
    __syncthreads();

#pragma unroll
    for (int mt = 0; mt < 4; ++mt) {
        acc[mt][0] = (f32x4){0.f, 0.f, 0.f, 0.f};
        acc[mt][1] = (f32x4){0.f, 0.f, 0.f, 0.f};
    }
#pragma unroll
    for (int kt = 0; kt < 4; ++kt) {
        const int kk = kt * 32 + kq;
        bf16x8 bw0 = *(const bf16x8*)(fU2 + (size_t)(((kt * 8 + nt0) * 64 + lane) * 8));
        bf16x8 bw1 = *(const bf16x8*)(fU2 + (size_t)(((kt * 8 + nt0 + 1) * 64 + lane) * 8));
#pragma unroll
        for (int mt = 0; mt < 4; ++mt) {
            bf16x8 a = *(const bf16x8*)(&sB[0][0] + (mt * 16 + mrow) * 136 + kk);
            acc[mt][0] = MFMA(a, bw0, acc[mt][0]);
            acc[mt][1] = MFMA(a, bw1, acc[mt][1]);
        }
    }
#pragma unroll
    for (int mt = 0; mt < 4; ++mt) {
#pragma unroll
        for (int n2 = 0; n2 < 2; ++n2) {
            const int col = (nt0 + n2) * 16 + ccol;
            const float bb = bf2f(bu2[col]);
#pragma unroll
            for (int r = 0; r < 4; ++r) {
                const int row = mt * 16 + crow + r;
                const size_t idx = (size_t)(row0 + row) * HH + col;
                if (isf) {
                    float base = ((const float*)rawfeat)[idx];
                    ((float*)outp)[idx] = acc[mt][n2][r] + bb + base;
                } else {
                    float base = bf2f(sA[row][col]);
                    ((u16*)outp)[idx] = f2bf(acc[mt][n2][r] + bb + base);
                }
            }
        }
    }

    // fused positions output: 3 elems per node row (192 per block)
    if (tid < 192) {
        int i = row0 * 3 + tid;
        float x = pacc[i];
        if (isf) {
            float base = ((const float*)rawpos)[i];
            ((float*)outp)[5120000 + i] = base + 0.5f * x;
        } else {
            float base = bf2f(((const u16*)rawpos)[i]);
            ((u16*)outp)[5120000 + i] = f2bf(base + 0.5f * x);
        }
    }
}

extern "C" void kernel_launch(void* const* d_in, const int* in_sizes, int n_in,
                              void* d_out, int out_size, void* d_ws, size_t ws_size,
                              hipStream_t stream)
{
    // ws layout (bytes): same offsets as previous rounds; ws_msg region now
    // holds bf16 message output (10.24 MB used of 20.48), no zeroing needed.
    u16*   ws_msg  = (u16*)d_ws;
    float* ws_pos  = (float*)((char*)d_ws + 20480000);
    int*   cnt_up  = (int*)((char*)d_ws + 20960000);
    int*   cnt_dn  = (int*)((char*)d_ws + 21040000);
    int*   cur_up  = (int*)((char*)d_ws + 21120000);
    int*   cur_dn  = (int*)((char*)d_ws + 21200000);
    int*   bsum_up = (int*)((char*)d_ws + 21280000);
    int*   bsum_dn = (int*)((char*)d_ws + 21280400);
    int*   es_up   = (int*)((char*)d_ws + 21280800);
    int*   es_dn   = (int*)((char*)d_ws + 22080800);
    u16*   fbase   = (u16*)((char*)d_ws + 22880800);
    u16*   canon   = (u16*)((char*)d_ws + 23241248);
    int*   flag    = (int*)((char*)d_ws + 33804328);
    if (ws_size < 33804332ULL) return;

    u16* f_m1u = fbase;              // 32768 (K=256)
    u16* f_m2u = fbase + 32768;
    u16* f_p1u = fbase + 49152;      // fused W2@P1 frags (overwritten by gemm_fuse)
    u16* f_m1d = fbase + 65536;
    u16* f_m2d = fbase + 98304;
    u16* f_p1d = fbase + 114688;     // fused W2@P1 frags
    u16* f_u1  = fbase + 131072;
    u16* f_u2  = fbase + 163840;

    u16* cfeat  = canon;
    u16* cpos   = canon + 5120000;
    u16* cdgu   = canon + 5240000;
    u16* cdgd   = canon + 5260000;
    u16* cw1lu  = canon + 5280000;
    u16* cb1u   = canon + 5280128;
    u16* cb2u   = canon + 5280256;
    u16* cbp1u  = canon + 5280384;   // fused bias b2@P1+bp1 (overwritten by gemm_fuse)
    u16* cwp2u  = canon + 5280512;
    u16* cbp2u  = canon + 5280640;
    u16* cw1ld  = canon + 5280642;
    u16* cb1d   = canon + 5280770;
    u16* cb2d   = canon + 5280898;
    u16* cbp1d  = canon + 5281026;   // fused bias
    u16* cwp2d  = canon + 5281154;
    u16* cbp2d  = canon + 5281282;
    u16* cbu1   = canon + 5281284;
    u16* cbu2   = canon + 5281412;

    const int* ei_up = (const int*)d_in[2];
    const int* ei_dn = (const int*)d_in[3];

    // launch 1: detect dtype + zero CSR counters
    detect_zero_kernel<<<157, 256, 0, stream>>>((const u16*)d_in[0], flag, cnt_up);

    // launch 2: fused setup (canon | frags | edge counts) — no ws zeroing
    P18 cp;
    cp.p[0] = d_in[0];  cp.p[1] = d_in[1];  cp.p[2] = d_in[4];  cp.p[3] = d_in[5];
    cp.p[4] = d_in[6];  cp.p[5] = d_in[7];  cp.p[6] = d_in[9];  cp.p[7] = d_in[11];
    cp.p[8] = d_in[12]; cp.p[9] = d_in[13];
    cp.p[10] = d_in[14]; cp.p[11] = d_in[15]; cp.p[12] = d_in[17]; cp.p[13] = d_in[19];
    cp.p[14] = d_in[20]; cp.p[15] = d_in[21];
    cp.p[16] = d_in[23]; cp.p[17] = d_in[25];
    P8 wsf;
    wsf.w[0] = d_in[6];  wsf.w[1] = d_in[8];  wsf.w[2] = d_in[10]; wsf.w[3] = d_in[14];
    wsf.w[4] = d_in[16]; wsf.w[5] = d_in[18]; wsf.w[6] = d_in[22]; wsf.w[7] = d_in[24];
    setup_kernel<<<(S3 + 255) / 256, 256, 0, stream>>>(cp, wsf, ei_up, ei_dn,
                                                       canon, fbase,
                                                       cnt_up, cnt_dn, flag);

    // launch 2b: W2@P1 fusion (overwrites f_p1 frags + cbp1 bias slots)
    gemm_fuse_kernel<<<128, 256, 0, stream>>>(d_in[8], d_in[10], d_in[9], d_in[11],
                                              d_in[16], d_in[18], d_in[17], d_in[19],
                                              f_p1u, f_p1d, cbp1u, cbp1d, flag);

    // launches 3-5: CSR scan + scatter
    SP sp;
    sp.cnt[0] = cnt_up; sp.cnt[1] = cnt_dn;
    sp.cur[0] = cur_up; sp.cur[1] = cur_dn;
    sp.bsum[0] = bsum_up; sp.bsum[1] = bsum_dn;
    scan1_kernel<<<2 * NBLK, 256, 0, stream>>>(sp);
    scan2_kernel<<<1, 256, 0, stream>>>(bsum_up, bsum_dn);
    scatter2_kernel<<<(2 * EE + 255) / 256, 256, 0, stream>>>(ei_up, ei_dn, cur_up, bsum_up,
                                                              cur_dn, bsum_dn, es_up, es_dn);

    // launch 6: edge kernel (dst-tile ownership, zero global atomics)
    EP2 up, dn;
    up.eidx = ei_up; up.es = es_up; up.deg = cdgu;
    up.cnt = cnt_up; up.cur = cur_up; up.bsum = bsum_up;
    up.fW1 = f_m1u; up.fW2 = f_m2u;
    up.w1last = cw1lu; up.bias1 = cb1u; up.bias2 = cb2u;
    up.biasp1 = cbp1u; up.wp2 = cwp2u; up.biasp2 = cbp2u;
    dn.eidx = ei_dn; dn.es = es_dn; dn.deg = cdgd;
    dn.cnt = cnt_dn; dn.cur = cur_dn; dn.bsum = bsum_dn;
    dn.fW1 = f_m1d; dn.fW2 = f_m2d;
    dn.w1last = cw1ld; dn.bias1 = cb1d; dn.bias2 = cb2d;
    dn.biasp1 = cbp1d; dn.wp2 = cwp2d; dn.biasp2 = cbp2d;
    edge_kernel<<<BB * NTIL, 512, 0, stream>>>(cfeat, cpos, up, dn, ws_msg, ws_pos);

    // launch 7: update + positions out
    update_kernel<<<625, 256, 0, stream>>>(d_in[0], d_in[1], f_u1, cbu1, f_u2, cbu2,
                                           d_out, ws_msg, ws_pos, flag);
}

// Round 11
// 457.516 us; speedup vs baseline: 1.6005x; 1.6005x over previous
//
#include <hip/hip_runtime.h>

#define BB 2
#define NN 20000
#define HH 128
#define EE 200000
#define TR 64       // edge rows per block (64 -> 3 blocks/CU on LDS)
#define NEB 3125    // EE/64 exact
#define NBLK 79     // ceil(NN/256)
#define NWG (2 * BB * NEB)   // 12500

typedef unsigned short u16;
typedef __attribute__((ext_vector_type(4))) float f32x4;
typedef __bf16 bf16x8 __attribute__((ext_vector_type(8)));

#define MFMA(a, b, c) __builtin_amdgcn_mfma_f32_16x16x32_bf16((a), (b), (c), 0, 0, 0)

__device__ __forceinline__ float bf2f(u16 u) {
    union { unsigned int i; float f; } v; v.i = ((unsigned int)u) << 16; return v.f;
}
__device__ __forceinline__ u16 f2bf(float f) {
    union { __bf16 h; u16 u; } v; v.h = (__bf16)f; return v.u;
}
#if __has_builtin(__builtin_amdgcn_rcpf)
__device__ __forceinline__ float rcpf(float x) { return __builtin_amdgcn_rcpf(x); }
#else
__device__ __forceinline__ float rcpf(float x) { return 1.f / x; }
#endif
__device__ __forceinline__ float silu_f(float z) { return z * rcpf(1.f + __expf(-z)); }
// flag-routed load (setup kernels only): f32 raw or bf16 raw
__device__ __forceinline__ float ldv(const void* p, long i, int f) {
    return f ? ((const float*)p)[i] : bf2f(((const u16*)p)[i]);
}

// ---------------- launch 1: dtype detection (cnt zeroing now via memset) ----------------
__global__ __launch_bounds__(256) void detect_kernel(const u16* __restrict__ f,
                                                     int* __restrict__ flag) {
    int tid = threadIdx.x;
    u16 v = f[tid * 2];
    int e = (v >> 7) & 0xFF;
    int ok = (e >= 101 && e <= 143) ? 1 : 0;
    __shared__ int c;
    if (tid == 0) c = 0;
    __syncthreads();
    atomicAdd(&c, ok);
    __syncthreads();
    if (tid == 0) *flag = (c < 200) ? 1 : 0;   // 1 => inputs are float32
}

// ---------------- launch 2: fused setup (canon | frags | edge counts) ----------------
#define C5TOT 5281540
#define FTOT 180224
#define S1 C5TOT
#define S2 (S1 + FTOT)
#define S3 (S2 + 2 * EE)
struct P18 { const void* p[18]; };
struct P8 { const void* w[8]; };

__global__ __launch_bounds__(256) void setup_kernel(
    P18 cp, P8 wf, const int* __restrict__ eu, const int* __restrict__ ed,
    u16* __restrict__ canon, u16* __restrict__ fbase,
    int* __restrict__ cnt_up, int* __restrict__ cnt_dn, const int* __restrict__ flag)
{
    long i = (long)blockIdx.x * 256 + threadIdx.x;
    if (i < S1) {
        static const int off[19] = {
            0, 5120000, 5240000, 5260000, 5280000,
            5280128, 5280256, 5280384, 5280512, 5280640,
            5280642, 5280770, 5280898, 5281026, 5281154, 5281282,
            5281284, 5281412, 5281540 };
        static const int rsz[18] = {
            5120000, 120000, 20000, 20000,
            128, 128, 128, 128, 128, 1,
            128, 128, 128, 128, 128, 1,
            128, 128 };
        static const int soff[18] = {
            0, 0, 0, 0,
            32768, 0, 0, 0, 0, 0,
            32768, 0, 0, 0, 0, 0,
            0, 0 };
        int j = (int)i;
        int isf = *flag;
        int t = 0;
#pragma unroll 1
        while (j >= off[t + 1]) ++t;
        int k = j - off[t];
        u16 v = 0;
        if (k < rsz[t]) v = f2bf(ldv(cp.p[t], (long)soff[t] + k, isf));
        canon[j] = v;
        return;
    }
    if (i < S2) {
        static const int foff[9] = { 0, 32768, 49152, 65536, 98304, 114688,
                                     131072, 163840, 180224 };
        int j = (int)(i - S1);
        int isf = *flag;
        int t = 0;
#pragma unroll 1
        while (j >= foff[t + 1]) ++t;
        int m = j - foff[t];
        int jj = m & 7, lane = (m >> 3) & 63, nt = (m >> 9) & 7, kt = m >> 12;
        int k = kt * 32 + ((lane >> 4) * 8) + jj;
        int n = nt * 16 + (lane & 15);
        fbase[j] = f2bf(ldv(wf.w[t], (long)k * 128 + n, isf));
        return;
    }
    if (i < S3) {
        int e = (int)(i - S2);
        if (e < EE) atomicAdd(&cnt_up[eu[EE + e]], 1);
        else atomicAdd(&cnt_dn[ed[EE + e - EE]], 1);
    }
}

// ---------------- launch 2b: W2@P1 fusion precompute ----------------
__global__ __launch_bounds__(256) void gemm_fuse_kernel(
    const void* __restrict__ w2u, const void* __restrict__ p1u,
    const void* __restrict__ b2u, const void* __restrict__ bp1u,
    const void* __restrict__ w2d, const void* __restrict__ p1d,
    const void* __restrict__ b2d, const void* __restrict__ bp1d,
    u16* __restrict__ fragu, u16* __restrict__ fragd,
    u16* __restrict__ cbp1u, u16* __restrict__ cbp1d,
    const int* __restrict__ flag)
{
    const int dir = blockIdx.x >> 6;                 // 64 blocks per direction
    const int idx = (blockIdx.x & 63) * 256 + threadIdx.x;   // 0..16383
    const int k = idx >> 7, n = idx & 127;
    const int isf = *flag;
    const void* W2 = dir ? w2d : w2u;
    const void* P1 = dir ? p1d : p1u;
    float s = 0.f;
#pragma unroll 4
    for (int m = 0; m < 128; ++m)
        s += ldv(W2, (long)k * 128 + m, isf) * ldv(P1, (long)m * 128 + n, isf);
    u16* dst = dir ? fragd : fragu;
    dst[(((k >> 5) * 8 + (n >> 4)) * 64 + ((k >> 3) & 3) * 16 + (n & 15)) * 8 + (k & 7)] = f2bf(s);
    if (idx < 128) {
        const void* B2 = dir ? b2d : b2u;
        const void* BP1 = dir ? bp1d : bp1u;
        float t = 0.f;
#pragma unroll 4
        for (int m = 0; m < 128; ++m)
            t += ldv(B2, m, isf) * ldv(P1, (long)m * 128 + idx, isf);
        (dir ? cbp1d : cbp1u)[idx] = f2bf(t + ldv(BP1, idx, isf));
    }
}

// ---------------- CSR scans + scatter ----------------
struct SP { const int* cnt[2]; int* cur[2]; int* bsum[2]; };

__global__ __launch_bounds__(256) void scan1_kernel(SP p) {
    int half = blockIdx.x / NBLK;
    int b = blockIdx.x - half * NBLK;
    int t = threadIdx.x;
    int i = b * 256 + t;
    __shared__ int buf[256];
    int v = (i < NN) ? p.cnt[half][i] : 0;
    buf[t] = v;
    __syncthreads();
    for (int s = 1; s < 256; s <<= 1) {
        int x = (t >= s) ? buf[t - s] : 0;
        __syncthreads();
        buf[t] += x;
        __syncthreads();
    }
    if (i < NN) p.cur[half][i] = buf[t] - v;   // exclusive within block
    if (t == 255) p.bsum[half][b] = buf[255];
}

__global__ __launch_bounds__(256) void scan2_kernel(int* __restrict__ bu, int* __restrict__ bd) {
    __shared__ int buf[2][128];
    int half = threadIdx.x >> 7, t = threadIdx.x & 127;
    int* bs = half ? bd : bu;
    int v = (t < NBLK) ? bs[t] : 0;
    buf[half][t] = v;
    __syncthreads();
    for (int s = 1; s < 128; s <<= 1) {
        int x = (t >= s) ? buf[half][t - s] : 0;
        __syncthreads();
        buf[half][t] += x;
        __syncthreads();
    }
    if (t < NBLK) bs[t] = buf[half][t] - v;    // exclusive block offsets
}

__global__ void scatter2_kernel(const int* __restrict__ eu, const int* __restrict__ ed,
                                int* __restrict__ cu, const int* __restrict__ bu,
                                int* __restrict__ cd, const int* __restrict__ bd,
                                int* __restrict__ su, int* __restrict__ sd) {
    int e = blockIdx.x * 256 + threadIdx.x;
    if (e < EE) {
        int d = eu[EE + e];
        int p = atomicAdd(&cu[d], 1) + bu[d >> 8];
        su[p] = e;
    } else {
        e -= EE;
        if (e < EE) {
            int d = ed[EE + e];
            int p = atomicAdd(&cd[d], 1) + bd[d >> 8];
            sd[p] = e;
        }
    }
}

// ---------------- edge kernel: 64 rows/block, 3 blocks/CU, XCD-chunked ----------------
struct EP {
    const int* eidx; const int* es; const u16* deg;
    const u16* fW1; const u16* fW2;
    const u16* w1last; const u16* bias1; const u16* bias2;
    const u16* biasp1; const u16* wp2; const u16* biasp2;
};

// r8 structure (measured 275 us edge, 458.6 total): TR=64, 3 blocks/CU,
// XCD-chunked bijective swizzle, segment-reduced msg + pos atomics.
__global__ __launch_bounds__(512, 6) void edge_kernel(
    const u16* __restrict__ feat, const u16* __restrict__ posit,   // canonical bf16
    EP up, EP dn,
    float* __restrict__ msg_base, float* __restrict__ pos_base)
{
    const int tid = threadIdx.x;
    const int lane = tid & 63;
    const int wv = tid >> 6;
    const int bid0 = blockIdx.x;
    const int xcd = bid0 & 7;
    const int bid = (xcd < 4 ? xcd * 1563 : 4 * 1563 + (xcd - 4) * 1562) + (bid0 >> 3);
    const int half = bid / (BB * NEB);
    const int rem = bid - half * (BB * NEB);
    const int bb = rem / NEB;
    const int s0 = (rem - bb * NEB) * TR;
    const EP P = half ? dn : up;
    float* msg_acc = msg_base + (size_t)bb * NN * HH;
    float* pos_acc = pos_base + (size_t)bb * NN * 3;

    __shared__ u16 sA[TR][136];
    __shared__ u16 sB[TR][136];
    __shared__ u16 sC[TR][136];
    __shared__ float sInv[TR];
    __shared__ float sWgt[TR];
    __shared__ int sDst[TR];

    const int wm = wv >> 2;        // 0..1 : 32-row half
    const int wn = wv & 3;         // 0..3 : column quarter
    const int rbase = wm * 32;
    const int mrow = lane & 15;
    const int kq = (lane >> 4) * 8;
    const int crow = (lane >> 4) * 4;
    const int ccol = lane & 15;

    // gather + meta (8 threads/row, 32B each; part 0 also does meta)
    {
        const int r = tid >> 3, part = tid & 7;
        int slot = s0 + r; if (slot >= EE) slot = EE - 1;
        int e = P.es[slot];
        int s = P.eidx[e];
        int d = P.eidx[EE + e];
        if (part == 0) {
            sDst[r] = d;
            sInv[r] = 1.f / fmaxf(bf2f(P.deg[d]), 1.f);
            const u16* ps = posit + ((size_t)bb * NN + s) * 3;
            const u16* pd = posit + ((size_t)bb * NN + d) * 3;
            float dx = bf2f(ps[0]) - bf2f(pd[0]);
            float dy = bf2f(ps[1]) - bf2f(pd[1]);
            float dz = bf2f(ps[2]) - bf2f(pd[2]);
            *(float4*)&sC[r][128] =
                make_float4(sqrtf(dx * dx + dy * dy + dz * dz), dx, dy, dz);
        }
        const uint4* fs = (const uint4*)(feat + ((size_t)bb * NN + s) * HH);
        const uint4* fd = (const uint4*)(feat + ((size_t)bb * NN + d) * HH);
        uint4* as = (uint4*)&sA[r][part * 16];
        uint4* ad = (uint4*)&sB[r][part * 16];
#pragma unroll
        for (int i = 0; i < 2; ++i) { as[i] = fs[part * 2 + i]; ad[i] = fd[part * 2 + i]; }
    }
    __syncthreads();   // B1

    // ----- msg layer 1 : [h_src | h_dst] @ W1[0:256]  (K=256, 2mt x 2nt/wave) -----
    f32x4 acc[2][2];
#pragma unroll
    for (int mt = 0; mt < 2; ++mt) {
        acc[mt][0] = (f32x4){0.f, 0.f, 0.f, 0.f};
        acc[mt][1] = (f32x4){0.f, 0.f, 0.f, 0.f};
    }
#pragma unroll
    for (int kt = 0; kt < 8; ++kt) {
        const u16* Xb = (kt < 4) ? &sA[0][0] : &sB[0][0];
        const int kk = (kt & 3) * 32 + kq;
        bf16x8 bw0 = *(const bf16x8*)(P.fW1 + (size_t)(((kt * 8 + wn * 2) * 64 + lane) * 8));
        bf16x8 bw1 = *(const bf16x8*)(P.fW1 + (size_t)(((kt * 8 + wn * 2 + 1) * 64 + lane) * 8));
#pragma unroll
        for (int mt = 0; mt < 2; ++mt) {
            bf16x8 a = *(const bf16x8*)(Xb + (rbase + mt * 16 + mrow) * 136 + kk);
            acc[mt][0] = MFMA(a, bw0, acc[mt][0]);
            acc[mt][1] = MFMA(a, bw1, acc[mt][1]);
        }
    }

    // L1 epilogue: + dist*W1[256] + b1, silu -> sC (fresh buffer, no barrier)
#pragma unroll
    for (int n2 = 0; n2 < 2; ++n2) {
        const int col = (wn * 2 + n2) * 16 + ccol;
        const float wl = bf2f(P.w1last[col]);
        const float bb1 = bf2f(P.bias1[col]);
#pragma unroll
        for (int mt = 0; mt < 2; ++mt) {
#pragma unroll
            for (int r = 0; r < 4; ++r) {
                const int row = rbase + mt * 16 + crow + r;
                const float dist = ((const float*)&sC[row][128])[0];
                float z = fmaf(dist, wl, acc[mt][n2][r]) + bb1;
                sC[row][col] = f2bf(silu_f(z));
            }
        }
    }
    __syncthreads();   // B2: L1 hidden visible; sA/sB reads done

    // ----- fused pass : sC @ [W2 | W2@P1]  (K=128, 16 n-tiles, 2mt x 4nt/wave) -----
    f32x4 facc[2][4];
#pragma unroll
    for (int mt = 0; mt < 2; ++mt)
#pragma unroll
        for (int j = 0; j < 4; ++j) facc[mt][j] = (f32x4){0.f, 0.f, 0.f, 0.f};
    const int nt0 = wn * 4;
#pragma unroll
    for (int kt = 0; kt < 4; ++kt) {
        const int kk = kt * 32 + kq;
        bf16x8 bw[4];
#pragma unroll
        for (int j = 0; j < 4; ++j) {
            const int nt = nt0 + j;
            const size_t off = (nt & 8)
                ? (size_t)(16384 + ((kt * 8 + (nt & 7)) * 64 + lane) * 8)
                : (size_t)(((kt * 8 + nt) * 64 + lane) * 8);
            bw[j] = *(const bf16x8*)(P.fW2 + off);
        }
#pragma unroll
        for (int mt = 0; mt < 2; ++mt) {
            bf16x8 a = *(const bf16x8*)(&sC[0][0] + (rbase + mt * 16 + mrow) * 136 + kk);
#pragma unroll
            for (int j = 0; j < 4; ++j) facc[mt][j] = MFMA(a, bw[j], facc[mt][j]);
        }
    }

    // fused epilogue: wn<2 -> messages (sA, +b2); wn>=2 -> pos-hidden (sB, silu+fused bias)
    if (wn < 2) {
#pragma unroll
        for (int j = 0; j < 4; ++j) {
            const int col = (nt0 + j) * 16 + ccol;
            const float b2v = bf2f(P.bias2[col]);
#pragma unroll
            for (int mt = 0; mt < 2; ++mt) {
#pragma unroll
                for (int r = 0; r < 4; ++r) {
                    const int row = rbase + mt * 16 + crow + r;
                    sA[row][col] = f2bf(facc[mt][j][r] + b2v);
                }
            }
        }
    } else {
#pragma unroll
        for (int j = 0; j < 4; ++j) {
            const int col = (nt0 - 8 + j) * 16 + ccol;
            const float fbv = bf2f(P.biasp1[col]);   // fused bias b2@P1 + bp1
#pragma unroll
            for (int mt = 0; mt < 2; ++mt) {
#pragma unroll
                for (int r = 0; r < 4; ++r) {
                    const int row = rbase + mt * 16 + crow + r;
                    sB[row][col] = f2bf(silu_f(facc[mt][j][r] + fbv));
                }
            }
        }
    }
    __syncthreads();   // B3: messages + pos-hidden visible

    // segment-reduced scatter of messages (rows sorted by dst)
    {
        const int scol = tid & 127;
        const int r0 = (tid >> 7) * 16;
        float vals[16];
#pragma unroll
        for (int j = 0; j < 16; ++j) vals[j] = bf2f(sA[r0 + j][scol]);
        float accv = 0.f;
        int dprev = sDst[r0];
        float invprev = sInv[r0];
#pragma unroll
        for (int j = 0; j < 16; ++j) {
            const int r = r0 + j;
            int dcur = sDst[r];
            if (dcur != dprev) {
                unsafeAtomicAdd(&msg_acc[(size_t)dprev * HH + scol], accv * invprev);
                accv = 0.f; dprev = dcur; invprev = sInv[r];
            }
            accv += (s0 + r < EE) ? vals[j] : 0.f;
        }
        unsafeAtomicAdd(&msg_acc[(size_t)dprev * HH + scol], accv * invprev);
    }

    // ----- pos layer 2 : tanh(hidden @ p2 + bp2) -> sWgt (no atomics yet) -----
    {
        const int r = tid >> 2, q = tid & 3;   // 4 threads/row, 32 cols each
        if (r < TR) {
            const unsigned* t32 = (const unsigned*)&sB[r][q * 32];
            const unsigned* w32 = (const unsigned*)(P.wp2 + q * 32);
            float p = 0.f;
#pragma unroll
            for (int k = 0; k < 16; ++k) {
                unsigned a = t32[k], b = w32[k];
                union { unsigned i; float f; } al, ah, bl, bh;
                al.i = a << 16; ah.i = a & 0xffff0000u;
                bl.i = b << 16; bh.i = b & 0xffff0000u;
                p = fmaf(al.f, bl.f, p);
                p = fmaf(ah.f, bh.f, p);
            }
            p += __shfl_xor(p, 1);
            p += __shfl_xor(p, 2);
            if (q == 0)
                sWgt[r] = (s0 + r < EE) ? tanhf(p + bf2f(P.biasp2[0])) : 0.f;
        }
    }
    __syncthreads();   // B4: sWgt visible

    // segment-reduced pos scatter: 12 threads = 3 comps x 4 spans of 16 rows
    if (tid < 12) {
        const int comp = tid % 3;
        const int r0 = (tid / 3) * 16;
        float accv = 0.f;
        int dprev = sDst[r0];
#pragma unroll
        for (int j = 0; j < 16; ++j) {
            const int r = r0 + j;
            int dcur = sDst[r];
            if (dcur != dprev) {
                if (accv != 0.f) unsafeAtomicAdd(&pos_acc[(size_t)dprev * 3 + comp], accv);
                accv = 0.f; dprev = dcur;
            }
            accv += sWgt[r] * ((const float*)&sC[r][128])[1 + comp];
        }
        if (accv != 0.f) unsafeAtomicAdd(&pos_acc[(size_t)dprev * 3 + comp], accv);
    }
}

// ---------------- update + fused pos output ----------------
__global__ __launch_bounds__(256) void update_kernel(
    const void* __restrict__ rawfeat, const void* __restrict__ rawpos,
    const u16* __restrict__ fU1, const u16* __restrict__ bu1,
    const u16* __restrict__ fU2, const u16* __restrict__ bu2,
    void* __restrict__ outp, const float* __restrict__ magg, const float* __restrict__ pacc,
    const int* __restrict__ flag)
{
    const int tid = threadIdx.x;
    const int lane = tid & 63;
    const int wv = tid >> 6;
    const int row0 = blockIdx.x * 64;
    const int isf = *flag;

    __shared__ u16 sA[64][136];   // features (bf16)
    __shared__ u16 sB[64][136];   // msg_acc -> hidden (reused)

    if (isf) {
        const float* fp = (const float*)rawfeat + (size_t)row0 * HH;
        for (int i = tid; i < 1024; i += 256) {
            int r = i >> 4, c = (i & 15) * 8;
            float4 v0 = *(const float4*)(fp + (size_t)r * HH + c);
            float4 v1 = *(const float4*)(fp + (size_t)r * HH + c + 4);
            uint4 o;
            o.x = (unsigned)f2bf(v0.x) | ((unsigned)f2bf(v0.y) << 16);
            o.y = (unsigned)f2bf(v0.z) | ((unsigned)f2bf(v0.w) << 16);
            o.z = (unsigned)f2bf(v1.x) | ((unsigned)f2bf(v1.y) << 16);
            o.w = (unsigned)f2bf(v1.z) | ((unsigned)f2bf(v1.w) << 16);
            *(uint4*)&sA[r][c] = o;
        }
    } else {
        const uint4* fp = (const uint4*)((const u16*)rawfeat + (size_t)row0 * HH);
        for (int i = tid; i < 1024; i += 256) {
            int r = i >> 4, c = i & 15;
            *(uint4*)&sA[r][c * 8] = fp[i];
        }
    }
    {
        const float4* am = (const float4*)(magg) + (size_t)row0 * 32;
        for (int i = tid; i < 2048; i += 256) {
            int r = i >> 5;
            float4 v = am[i];
            int c = (i & 31) * 4;
            sB[r][c + 0] = f2bf(v.x);
            sB[r][c + 1] = f2bf(v.y);
            sB[r][c + 2] = f2bf(v.z);
            sB[r][c + 3] = f2bf(v.w);
        }
    }
    __syncthreads();

    const int nt0 = wv * 2;
    const int mrow = lane & 15;
    const int kq = (lane >> 4) * 8;
    const int crow = (lane >> 4) * 4;
    const int ccol = lane & 15;

    f32x4 acc[4][2];
#pragma unroll
    for (int mt = 0; mt < 4; ++mt) {
        acc[mt][0] = (f32x4){0.f, 0.f, 0.f, 0.f};
        acc[mt][1] = (f32x4){0.f, 0.f, 0.f, 0.f};
    }
#pragma unroll
    for (int kt = 0; kt < 8; ++kt) {
        const u16* Xb = (kt < 4) ? &sA[0][0] : &sB[0][0];
        const int kk = (kt & 3) * 32 + kq;
        bf16x8 bw0 = *(const bf16x8*)(fU1 + (size_t)(((kt * 8 + nt0) * 64 + lane) * 8));
        bf16x8 bw1 = *(const bf16x8*)(fU1 + (size_t)(((kt * 8 + nt0 + 1) * 64 + lane) * 8));
#pragma unroll
        for (int mt = 0; mt < 4; ++mt) {
            bf16x8 a = *(const bf16x8*)(Xb + (mt * 16 + mrow) * 136 + kk);
            acc[mt][0] = MFMA(a, bw0, acc[mt][0]);
            acc[mt][1] = MFMA(a, bw1, acc[mt][1]);
        }
    }
    __syncthreads();

#pragma unroll
    for (int mt = 0; mt < 4; ++mt) {
#pragma unroll
        for (int n2 = 0; n2 < 2; ++n2) {
            const int col = (nt0 + n2) * 16 + ccol;
            const float bb = bf2f(bu1[col]);
#pragma unroll
            for (int r = 0; r < 4; ++r) {
                const int row = mt * 16 + crow + r;
                sB[row][col] = f2bf(silu_f(acc[mt][n2][r] + bb));
            }
        }
    }
    __syncthreads();

#pragma unroll
    for (int mt = 0; mt < 4; ++mt) {
        acc[mt][0] = (f32x4){0.f, 0.f, 0.f, 0.f};
        acc[mt][1] = (f32x4){0.f, 0.f, 0.f, 0.f};
    }
#pragma unroll
    for (int kt = 0; kt < 4; ++kt) {
        const int kk = kt * 32 + kq;
        bf16x8 bw0 = *(const bf16x8*)(fU2 + (size_t)(((kt * 8 + nt0) * 64 + lane) * 8));
        bf16x8 bw1 = *(const bf16x8*)(fU2 + (size_t)(((kt * 8 + nt0 + 1) * 64 + lane) * 8));
#pragma unroll
        for (int mt = 0; mt < 4; ++mt) {
            bf16x8 a = *(const bf16x8*)(&sB[0][0] + (mt * 16 + mrow) * 136 + kk);
            acc[mt][0] = MFMA(a, bw0, acc[mt][0]);
            acc[mt][1] = MFMA(a, bw1, acc[mt][1]);
        }
    }
#pragma unroll
    for (int mt = 0; mt < 4; ++mt) {
#pragma unroll
        for (int n2 = 0; n2 < 2; ++n2) {
            const int col = (nt0 + n2) * 16 + ccol;
            const float bb = bf2f(bu2[col]);
#pragma unroll
            for (int r = 0; r < 4; ++r) {
                const int row = mt * 16 + crow + r;
                const size_t idx = (size_t)(row0 + row) * HH + col;
                if (isf) {
                    float base = ((const float*)rawfeat)[idx];
                    ((float*)outp)[idx] = acc[mt][n2][r] + bb + base;
                } else {
                    float base = bf2f(sA[row][col]);
                    ((u16*)outp)[idx] = f2bf(acc[mt][n2][r] + bb + base);
                }
            }
        }
    }

    // fused positions output: 3 elems per node row (192 per block)
    if (tid < 192) {
        int i = row0 * 3 + tid;
        float x = pacc[i];
        if (isf) {
            float base = ((const float*)rawpos)[i];
            ((float*)outp)[5120000 + i] = base + 0.5f * x;
        } else {
            float base = bf2f(((const u16*)rawpos)[i]);
            ((u16*)outp)[5120000 + i] = f2bf(base + 0.5f * x);
        }
    }
}

extern "C" void kernel_launch(void* const* d_in, const int* in_sizes, int n_in,
                              void* d_out, int out_size, void* d_ws, size_t ws_size,
                              hipStream_t stream)
{
    // ws layout (bytes): identical to previous rounds
    float* ws_msg  = (float*)d_ws;
    float* ws_pos  = (float*)((char*)d_ws + 20480000);
    int*   cnt_up  = (int*)((char*)d_ws + 20960000);
    int*   cnt_dn  = (int*)((char*)d_ws + 21040000);
    int*   cur_up  = (int*)((char*)d_ws + 21120000);
    int*   cur_dn  = (int*)((char*)d_ws + 21200000);
    int*   bsum_up = (int*)((char*)d_ws + 21280000);
    int*   bsum_dn = (int*)((char*)d_ws + 21280400);
    int*   es_up   = (int*)((char*)d_ws + 21280800);
    int*   es_dn   = (int*)((char*)d_ws + 22080800);
    u16*   fbase   = (u16*)((char*)d_ws + 22880800);
    u16*   canon   = (u16*)((char*)d_ws + 23241248);
    int*   flag    = (int*)((char*)d_ws + 33804328);
    if (ws_size < 33804332ULL) return;

    u16* f_m1u = fbase;              // 32768 (K=256)
    u16* f_m2u = fbase + 32768;
    u16* f_p1u = fbase + 49152;      // fused W2@P1 frags (overwritten by gemm_fuse)
    u16* f_m1d = fbase + 65536;
    u16* f_m2d = fbase + 98304;
    u16* f_p1d = fbase + 114688;     // fused W2@P1 frags
    u16* f_u1  = fbase + 131072;
    u16* f_u2  = fbase + 163840;

    u16* cfeat  = canon;
    u16* cpos   = canon + 5120000;
    u16* cdgu   = canon + 5240000;
    u16* cdgd   = canon + 5260000;
    u16* cw1lu  = canon + 5280000;
    u16* cb1u   = canon + 5280128;
    u16* cb2u   = canon + 5280256;
    u16* cbp1u  = canon + 5280384;   // fused bias b2@P1+bp1 (overwritten by gemm_fuse)
    u16* cwp2u  = canon + 5280512;
    u16* cbp2u  = canon + 5280640;
    u16* cw1ld  = canon + 5280642;
    u16* cb1d   = canon + 5280770;
    u16* cb2d   = canon + 5280898;
    u16* cbp1d  = canon + 5281026;   // fused bias
    u16* cwp2d  = canon + 5281154;
    u16* cbp2d  = canon + 5281282;
    u16* cbu1   = canon + 5281284;
    u16* cbu2   = canon + 5281412;

    const int* ei_up = (const int*)d_in[2];
    const int* ei_dn = (const int*)d_in[3];

    // launch 0: DMA-zero ws_msg + ws_pos + cnt_up/cnt_dn (21.12 MB) on the
    // copy engine instead of 5.28M setup threads (stream-ordered, capture-safe)
    hipMemsetAsync(d_ws, 0, 21120000, stream);

    // launch 1: detect dtype (flag only)
    detect_kernel<<<1, 256, 0, stream>>>((const u16*)d_in[0], flag);

    // launch 2: fused setup (canon | frags | edge counts) — no ws zeroing
    P18 cp;
    cp.p[0] = d_in[0];  cp.p[1] = d_in[1];  cp.p[2] = d_in[4];  cp.p[3] = d_in[5];
    cp.p[4] = d_in[6];  cp.p[5] = d_in[7];  cp.p[6] = d_in[9];  cp.p[7] = d_in[11];
    cp.p[8] = d_in[12]; cp.p[9] = d_in[13];
    cp.p[10] = d_in[14]; cp.p[11] = d_in[15]; cp.p[12] = d_in[17]; cp.p[13] = d_in[19];
    cp.p[14] = d_in[20]; cp.p[15] = d_in[21];
    cp.p[16] = d_in[23]; cp.p[17] = d_in[25];
    P8 wsf;
    wsf.w[0] = d_in[6];  wsf.w[1] = d_in[8];  wsf.w[2] = d_in[10]; wsf.w[3] = d_in[14];
    wsf.w[4] = d_in[16]; wsf.w[5] = d_in[18]; wsf.w[6] = d_in[22]; wsf.w[7] = d_in[24];
    setup_kernel<<<(S3 + 255) / 256, 256, 0, stream>>>(cp, wsf, ei_up, ei_dn,
                                                       canon, fbase,
                                                       cnt_up, cnt_dn, flag);

    // launch 2b: W2@P1 fusion (overwrites f_p1 frags + cbp1 bias slots)
    gemm_fuse_kernel<<<128, 256, 0, stream>>>(d_in[8], d_in[10], d_in[9], d_in[11],
                                              d_in[16], d_in[18], d_in[17], d_in[19],
                                              f_p1u, f_p1d, cbp1u, cbp1d, flag);

    // launches 3-5: CSR scan + scatter
    SP sp;
    sp.cnt[0] = cnt_up; sp.cnt[1] = cnt_dn;
    sp.cur[0] = cur_up; sp.cur[1] = cur_dn;
    sp.bsum[0] = bsum_up; sp.bsum[1] = bsum_dn;
    scan1_kernel<<<2 * NBLK, 256, 0, stream>>>(sp);
    scan2_kernel<<<1, 256, 0, stream>>>(bsum_up, bsum_dn);
    scatter2_kernel<<<(2 * EE + 255) / 256, 256, 0, stream>>>(ei_up, ei_dn, cur_up, bsum_up,
                                                              cur_dn, bsum_dn, es_up, es_dn);

    // launch 6: edge kernel (r8 structure: TR=64, 3 blocks/CU, XCD swizzle)
    EP up, dn;
    up.eidx = ei_up; up.es = es_up; up.deg = cdgu;
    up.fW1 = f_m1u; up.fW2 = f_m2u;
    up.w1last = cw1lu; up.bias1 = cb1u; up.bias2 = cb2u;
    up.biasp1 = cbp1u; up.wp2 = cwp2u; up.biasp2 = cbp2u;
    dn.eidx = ei_dn; dn.es = es_dn; dn.deg = cdgd;
    dn.fW1 = f_m1d; dn.fW2 = f_m2d;
    dn.w1last = cw1ld; dn.bias1 = cb1d; dn.bias2 = cb2d;
    dn.biasp1 = cbp1d; dn.wp2 = cwp2d; dn.biasp2 = cbp2d;
    edge_kernel<<<NWG, 512, 0, stream>>>(cfeat, cpos, up, dn, ws_msg, ws_pos);

    // launch 7: update + positions out
    update_kernel<<<625, 256, 0, stream>>>(d_in[0], d_in[1], f_u1, cbu1, f_u2, cbu2,
                                           d_out, ws_msg, ws_pos, flag);
}

// Round 12
// 455.060 us; speedup vs baseline: 1.6092x; 1.0054x over previous
//
#include <hip/hip_runtime.h>

#define BB 2
#define NN 20000
#define HH 128
#define EE 200000
#define TR 64       // edge rows per block (64 -> 3 blocks/CU on LDS)
#define NEB 3125    // EE/64 exact
#define NBLK 79     // ceil(NN/256)
#define NWG (2 * BB * NEB)   // 12500

typedef unsigned short u16;
typedef __attribute__((ext_vector_type(4))) float f32x4;
typedef __bf16 bf16x8 __attribute__((ext_vector_type(8)));

#define MFMA(a, b, c) __builtin_amdgcn_mfma_f32_16x16x32_bf16((a), (b), (c), 0, 0, 0)

__device__ __forceinline__ float bf2f(u16 u) {
    union { unsigned int i; float f; } v; v.i = ((unsigned int)u) << 16; return v.f;
}
__device__ __forceinline__ u16 f2bf(float f) {
    union { __bf16 h; u16 u; } v; v.h = (__bf16)f; return v.u;
}
#if __has_builtin(__builtin_amdgcn_rcpf)
__device__ __forceinline__ float rcpf(float x) { return __builtin_amdgcn_rcpf(x); }
#else
__device__ __forceinline__ float rcpf(float x) { return 1.f / x; }
#endif
__device__ __forceinline__ float silu_f(float z) { return z * rcpf(1.f + __expf(-z)); }
// flag-routed load (setup kernels only): f32 raw or bf16 raw
__device__ __forceinline__ float ldv(const void* p, long i, int f) {
    return f ? ((const float*)p)[i] : bf2f(((const u16*)p)[i]);
}

// ---------------- launch 1: dtype detection (cnt zeroing via memset) ----------------
__global__ __launch_bounds__(256) void detect_kernel(const u16* __restrict__ f,
                                                     int* __restrict__ flag) {
    int tid = threadIdx.x;
    u16 v = f[tid * 2];
    int e = (v >> 7) & 0xFF;
    int ok = (e >= 101 && e <= 143) ? 1 : 0;
    __shared__ int c;
    if (tid == 0) c = 0;
    __syncthreads();
    atomicAdd(&c, ok);
    __syncthreads();
    if (tid == 0) *flag = (c < 200) ? 1 : 0;   // 1 => inputs are float32
}

// ---------------- launch 2: fused setup (canon | frags | edge counts) ----------------
// feat+pos canon region (5.24M elems) vectorized 8/thread; rest scalar.
#define C5TOT 5281540
#define FTOT 180224
#define SV 655000                 // vec8 threads: 640000 feat + 15000 pos
#define SCT 41540                 // scalar canon tail (C5TOT - 5240000)
#define SB2 (SV + SCT)
#define SC2 (SB2 + FTOT)
#define SD2 (SC2 + 2 * EE)
struct P18 { const void* p[18]; };
struct P8 { const void* w[8]; };

__global__ __launch_bounds__(256) void setup_kernel(
    P18 cp, P8 wf, const int* __restrict__ eu, const int* __restrict__ ed,
    u16* __restrict__ canon, u16* __restrict__ fbase,
    int* __restrict__ cnt_up, int* __restrict__ cnt_dn, const int* __restrict__ flag)
{
    long i = (long)blockIdx.x * 256 + threadIdx.x;
    const int isf = *flag;
    if (i < SV) {
        // vec8 canon: feat (threads < 640000) then pos
        long j = i * 8;
        if (isf) {
            const float* src = (j < 5120000)
                ? (const float*)cp.p[0] + j
                : (const float*)cp.p[1] + (j - 5120000);
            float4 v0 = *(const float4*)src;
            float4 v1 = *(const float4*)(src + 4);
            uint4 o;
            o.x = (unsigned)f2bf(v0.x) | ((unsigned)f2bf(v0.y) << 16);
            o.y = (unsigned)f2bf(v0.z) | ((unsigned)f2bf(v0.w) << 16);
            o.z = (unsigned)f2bf(v1.x) | ((unsigned)f2bf(v1.y) << 16);
            o.w = (unsigned)f2bf(v1.z) | ((unsigned)f2bf(v1.w) << 16);
            *(uint4*)&canon[j] = o;
        } else {
            const u16* src = (j < 5120000)
                ? (const u16*)cp.p[0] + j
                : (const u16*)cp.p[1] + (j - 5120000);
            *(uint4*)&canon[j] = *(const uint4*)src;
        }
        return;
    }
    long k = i - SV;
    if (k < SCT) {
        // scalar canon tail: deg/params region, j in [5240000, C5TOT)
        static const int off[19] = {
            0, 5120000, 5240000, 5260000, 5280000,
            5280128, 5280256, 5280384, 5280512, 5280640,
            5280642, 5280770, 5280898, 5281026, 5281154, 5281282,
            5281284, 5281412, 5281540 };
        static const int rsz[18] = {
            5120000, 120000, 20000, 20000,
            128, 128, 128, 128, 128, 1,
            128, 128, 128, 128, 128, 1,
            128, 128 };
        static const int soff[18] = {
            0, 0, 0, 0,
            32768, 0, 0, 0, 0, 0,
            32768, 0, 0, 0, 0, 0,
            0, 0 };
        int j = 5240000 + (int)k;
        int t = 0;
#pragma unroll 1
        while (j >= off[t + 1]) ++t;
        int kk = j - off[t];
        u16 v = 0;
        if (kk < rsz[t]) v = f2bf(ldv(cp.p[t], (long)soff[t] + kk, isf));
        canon[j] = v;
        return;
    }
    k -= SCT;
    if (k < FTOT) {
        static const int foff[9] = { 0, 32768, 49152, 65536, 98304, 114688,
                                     131072, 163840, 180224 };
        int j = (int)k;
        int t = 0;
#pragma unroll 1
        while (j >= foff[t + 1]) ++t;
        int m = j - foff[t];
        int jj = m & 7, lane = (m >> 3) & 63, nt = (m >> 9) & 7, kt = m >> 12;
        int kr = kt * 32 + ((lane >> 4) * 8) + jj;
        int n = nt * 16 + (lane & 15);
        fbase[j] = f2bf(ldv(wf.w[t], (long)kr * 128 + n, isf));
        return;
    }
    k -= FTOT;
    if (k < 2 * EE) {
        int e = (int)k;
        if (e < EE) atomicAdd(&cnt_up[eu[EE + e]], 1);
        else atomicAdd(&cnt_dn[ed[EE + e - EE]], 1);
    }
}

// ---------------- launch 2b: W2@P1 fusion precompute ----------------
__global__ __launch_bounds__(256) void gemm_fuse_kernel(
    const void* __restrict__ w2u, const void* __restrict__ p1u,
    const void* __restrict__ b2u, const void* __restrict__ bp1u,
    const void* __restrict__ w2d, const void* __restrict__ p1d,
    const void* __restrict__ b2d, const void* __restrict__ bp1d,
    u16* __restrict__ fragu, u16* __restrict__ fragd,
    u16* __restrict__ cbp1u, u16* __restrict__ cbp1d,
    const int* __restrict__ flag)
{
    const int dir = blockIdx.x >> 6;                 // 64 blocks per direction
    const int idx = (blockIdx.x & 63) * 256 + threadIdx.x;   // 0..16383
    const int k = idx >> 7, n = idx & 127;
    const int isf = *flag;
    const void* W2 = dir ? w2d : w2u;
    const void* P1 = dir ? p1d : p1u;
    float s = 0.f;
#pragma unroll 4
    for (int m = 0; m < 128; ++m)
        s += ldv(W2, (long)k * 128 + m, isf) * ldv(P1, (long)m * 128 + n, isf);
    u16* dst = dir ? fragd : fragu;
    dst[(((k >> 5) * 8 + (n >> 4)) * 64 + ((k >> 3) & 3) * 16 + (n & 15)) * 8 + (k & 7)] = f2bf(s);
    if (idx < 128) {
        const void* B2 = dir ? b2d : b2u;
        const void* BP1 = dir ? bp1d : bp1u;
        float t = 0.f;
#pragma unroll 4
        for (int m = 0; m < 128; ++m)
            t += ldv(B2, m, isf) * ldv(P1, (long)m * 128 + idx, isf);
        (dir ? cbp1d : cbp1u)[idx] = f2bf(t + ldv(BP1, idx, isf));
    }
}

// ---------------- CSR scans + scatter ----------------
struct SP { const int* cnt[2]; int* cur[2]; int* bsum[2]; };

__global__ __launch_bounds__(256) void scan1_kernel(SP p) {
    int half = blockIdx.x / NBLK;
    int b = blockIdx.x - half * NBLK;
    int t = threadIdx.x;
    int i = b * 256 + t;
    __shared__ int buf[256];
    int v = (i < NN) ? p.cnt[half][i] : 0;
    buf[t] = v;
    __syncthreads();
    for (int s = 1; s < 256; s <<= 1) {
        int x = (t >= s) ? buf[t - s] : 0;
        __syncthreads();
        buf[t] += x;
        __syncthreads();
    }
    if (i < NN) p.cur[half][i] = buf[t] - v;   // exclusive within block
    if (t == 255) p.bsum[half][b] = buf[255];
}

__global__ __launch_bounds__(256) void scan2_kernel(int* __restrict__ bu, int* __restrict__ bd) {
    __shared__ int buf[2][128];
    int half = threadIdx.x >> 7, t = threadIdx.x & 127;
    int* bs = half ? bd : bu;
    int v = (t < NBLK) ? bs[t] : 0;
    buf[half][t] = v;
    __syncthreads();
    for (int s = 1; s < 128; s <<= 1) {
        int x = (t >= s) ? buf[half][t - s] : 0;
        __syncthreads();
        buf[half][t] += x;
        __syncthreads();
    }
    if (t < NBLK) bs[t] = buf[half][t] - v;    // exclusive block offsets
}

__global__ void scatter2_kernel(const int* __restrict__ eu, const int* __restrict__ ed,
                                int* __restrict__ cu, const int* __restrict__ bu,
                                int* __restrict__ cd, const int* __restrict__ bd,
                                int* __restrict__ su, int* __restrict__ sd) {
    int e = blockIdx.x * 256 + threadIdx.x;
    if (e < EE) {
        int d = eu[EE + e];
        int p = atomicAdd(&cu[d], 1) + bu[d >> 8];
        su[p] = e;
    } else {
        e -= EE;
        if (e < EE) {
            int d = ed[EE + e];
            int p = atomicAdd(&cd[d], 1) + bd[d >> 8];
            sd[p] = e;
        }
    }
}

// ---------------- edge kernel: 64 rows/block, 3 blocks/CU, XCD-chunked ----------------
struct EP {
    const int* eidx; const int* es; const u16* deg;
    const u16* fW1; const u16* fW2;
    const u16* w1last; const u16* bias1; const u16* bias2;
    const u16* biasp1; const u16* wp2; const u16* biasp2;
};

// r8/r11 structure + pos2 dot moved from VALU (130 insts/thread) to 8 MFMAs
// on the wn==0 waves (p2 as on-the-fly B-fragment, col 0 holds the dot).
__global__ __launch_bounds__(512, 6) void edge_kernel(
    const u16* __restrict__ feat, const u16* __restrict__ posit,   // canonical bf16
    EP up, EP dn,
    float* __restrict__ msg_base, float* __restrict__ pos_base)
{
    const int tid = threadIdx.x;
    const int lane = tid & 63;
    const int wv = tid >> 6;
    const int bid0 = blockIdx.x;
    const int xcd = bid0 & 7;
    const int bid = (xcd < 4 ? xcd * 1563 : 4 * 1563 + (xcd - 4) * 1562) + (bid0 >> 3);
    const int half = bid / (BB * NEB);
    const int rem = bid - half * (BB * NEB);
    const int bb = rem / NEB;
    const int s0 = (rem - bb * NEB) * TR;
    const EP P = half ? dn : up;
    float* msg_acc = msg_base + (size_t)bb * NN * HH;
    float* pos_acc = pos_base + (size_t)bb * NN * 3;

    __shared__ u16 sA[TR][136];
    __shared__ u16 sB[TR][136];
    __shared__ u16 sC[TR][136];
    __shared__ float sInv[TR];
    __shared__ float sWgt[TR];
    __shared__ int sDst[TR];

    const int wm = wv >> 2;        // 0..1 : 32-row half
    const int wn = wv & 3;         // 0..3 : column quarter
    const int rbase = wm * 32;
    const int mrow = lane & 15;
    const int kq = (lane >> 4) * 8;
    const int crow = (lane >> 4) * 4;
    const int ccol = lane & 15;

    // gather + meta (8 threads/row, 32B each; part 0 also does meta)
    {
        const int r = tid >> 3, part = tid & 7;
        int slot = s0 + r; if (slot >= EE) slot = EE - 1;
        int e = P.es[slot];
        int s = P.eidx[e];
        int d = P.eidx[EE + e];
        if (part == 0) {
            sDst[r] = d;
            sInv[r] = 1.f / fmaxf(bf2f(P.deg[d]), 1.f);
            const u16* ps = posit + ((size_t)bb * NN + s) * 3;
            const u16* pd = posit + ((size_t)bb * NN + d) * 3;
            float dx = bf2f(ps[0]) - bf2f(pd[0]);
            float dy = bf2f(ps[1]) - bf2f(pd[1]);
            float dz = bf2f(ps[2]) - bf2f(pd[2]);
            *(float4*)&sC[r][128] =
                make_float4(sqrtf(dx * dx + dy * dy + dz * dz), dx, dy, dz);
        }
        const uint4* fs = (const uint4*)(feat + ((size_t)bb * NN + s) * HH);
        const uint4* fd = (const uint4*)(feat + ((size_t)bb * NN + d) * HH);
        uint4* as = (uint4*)&sA[r][part * 16];
        uint4* ad = (uint4*)&sB[r][part * 16];
#pragma unroll
        for (int i = 0; i < 2; ++i) { as[i] = fs[part * 2 + i]; ad[i] = fd[part * 2 + i]; }
    }
    __syncthreads();   // B1

    // ----- msg layer 1 : [h_src | h_dst] @ W1[0:256]  (K=256, 2mt x 2nt/wave) -----
    f32x4 acc[2][2];
#pragma unroll
    for (int mt = 0; mt < 2; ++mt) {
        acc[mt][0] = (f32x4){0.f, 0.f, 0.f, 0.f};
        acc[mt][1] = (f32x4){0.f, 0.f, 0.f, 0.f};
    }
#pragma unroll
    for (int kt = 0; kt < 8; ++kt) {
        const u16* Xb = (kt < 4) ? &sA[0][0] : &sB[0][0];
        const int kk = (kt & 3) * 32 + kq;
        bf16x8 bw0 = *(const bf16x8*)(P.fW1 + (size_t)(((kt * 8 + wn * 2) * 64 + lane) * 8));
        bf16x8 bw1 = *(const bf16x8*)(P.fW1 + (size_t)(((kt * 8 + wn * 2 + 1) * 64 + lane) * 8));
#pragma unroll
        for (int mt = 0; mt < 2; ++mt) {
            bf16x8 a = *(const bf16x8*)(Xb + (rbase + mt * 16 + mrow) * 136 + kk);
            acc[mt][0] = MFMA(a, bw0, acc[mt][0]);
            acc[mt][1] = MFMA(a, bw1, acc[mt][1]);
        }
    }

    // L1 epilogue: + dist*W1[256] + b1, silu -> sC (fresh buffer, no barrier)
#pragma unroll
    for (int n2 = 0; n2 < 2; ++n2) {
        const int col = (wn * 2 + n2) * 16 + ccol;
        const float wl = bf2f(P.w1last[col]);
        const float bb1 = bf2f(P.bias1[col]);
#pragma unroll
        for (int mt = 0; mt < 2; ++mt) {
#pragma unroll
            for (int r = 0; r < 4; ++r) {
                const int row = rbase + mt * 16 + crow + r;
                const float dist = ((const float*)&sC[row][128])[0];
                float z = fmaf(dist, wl, acc[mt][n2][r]) + bb1;
                sC[row][col] = f2bf(silu_f(z));
            }
        }
    }
    __syncthreads();   // B2: L1 hidden visible; sA/sB reads done

    // ----- fused pass : sC @ [W2 | W2@P1]  (K=128, 16 n-tiles, 2mt x 4nt/wave) -----
    f32x4 facc[2][4];
#pragma unroll
    for (int mt = 0; mt < 2; ++mt)
#pragma unroll
        for (int j = 0; j < 4; ++j) facc[mt][j] = (f32x4){0.f, 0.f, 0.f, 0.f};
    const int nt0 = wn * 4;
#pragma unroll
    for (int kt = 0; kt < 4; ++kt) {
        const int kk = kt * 32 + kq;
        bf16x8 bw[4];
#pragma unroll
        for (int j = 0; j < 4; ++j) {
            const int nt = nt0 + j;
            const size_t off = (nt & 8)
                ? (size_t)(16384 + ((kt * 8 + (nt & 7)) * 64 + lane) * 8)
                : (size_t)(((kt * 8 + nt) * 64 + lane) * 8);
            bw[j] = *(const bf16x8*)(P.fW2 + off);
        }
#pragma unroll
        for (int mt = 0; mt < 2; ++mt) {
            bf16x8 a = *(const bf16x8*)(&sC[0][0] + (rbase + mt * 16 + mrow) * 136 + kk);
#pragma unroll
            for (int j = 0; j < 4; ++j) facc[mt][j] = MFMA(a, bw[j], facc[mt][j]);
        }
    }

    // fused epilogue: wn<2 -> messages (sA, +b2); wn>=2 -> pos-hidden (sB, silu+fused bias)
    if (wn < 2) {
#pragma unroll
        for (int j = 0; j < 4; ++j) {
            const int col = (nt0 + j) * 16 + ccol;
            const float b2v = bf2f(P.bias2[col]);
#pragma unroll
            for (int mt = 0; mt < 2; ++mt) {
#pragma unroll
                for (int r = 0; r < 4; ++r) {
                    const int row = rbase + mt * 16 + crow + r;
                    sA[row][col] = f2bf(facc[mt][j][r] + b2v);
                }
            }
        }
    } else {
#pragma unroll
        for (int j = 0; j < 4; ++j) {
            const int col = (nt0 - 8 + j) * 16 + ccol;
            const float fbv = bf2f(P.biasp1[col]);   // fused bias b2@P1 + bp1
#pragma unroll
            for (int mt = 0; mt < 2; ++mt) {
#pragma unroll
                for (int r = 0; r < 4; ++r) {
                    const int row = rbase + mt * 16 + crow + r;
                    sB[row][col] = f2bf(silu_f(facc[mt][j][r] + fbv));
                }
            }
        }
    }
    __syncthreads();   // B3: messages + pos-hidden visible

    // segment-reduced scatter of messages (rows sorted by dst)
    {
        const int scol = tid & 127;
        const int r0 = (tid >> 7) * 16;
        float vals[16];
#pragma unroll
        for (int j = 0; j < 16; ++j) vals[j] = bf2f(sA[r0 + j][scol]);
        float accv = 0.f;
        int dprev = sDst[r0];
        float invprev = sInv[r0];
#pragma unroll
        for (int j = 0; j < 16; ++j) {
            const int r = r0 + j;
            int dcur = sDst[r];
            if (dcur != dprev) {
                unsafeAtomicAdd(&msg_acc[(size_t)dprev * HH + scol], accv * invprev);
                accv = 0.f; dprev = dcur; invprev = sInv[r];
            }
            accv += (s0 + r < EE) ? vals[j] : 0.f;
        }
        unsafeAtomicAdd(&msg_acc[(size_t)dprev * HH + scol], accv * invprev);
    }

    // ----- pos layer 2 via MFMA (wn==0 waves): dot(pos-hidden, p2) -----
    if (wn == 0) {
        f32x4 pacc[2];
        pacc[0] = (f32x4){0.f, 0.f, 0.f, 0.f};
        pacc[1] = (f32x4){0.f, 0.f, 0.f, 0.f};
#pragma unroll
        for (int kt = 0; kt < 4; ++kt) {
            bf16x8 bp;
#pragma unroll
            for (int z = 0; z < 8; ++z) bp[z] = (__bf16)0.f;
            if ((lane & 15) == 0)
                bp = *(const bf16x8*)(P.wp2 + kt * 32 + (lane >> 4) * 8);
            const int kk = kt * 32 + kq;
#pragma unroll
            for (int mt = 0; mt < 2; ++mt) {
                bf16x8 a = *(const bf16x8*)(&sB[0][0] + (rbase + mt * 16 + mrow) * 136 + kk);
                pacc[mt] = MFMA(a, bp, pacc[mt]);
            }
        }
        if ((lane & 15) == 0) {
            const float bp2 = bf2f(P.biasp2[0]);
#pragma unroll
            for (int mt = 0; mt < 2; ++mt) {
#pragma unroll
                for (int r = 0; r < 4; ++r) {
                    const int row = rbase + mt * 16 + crow + r;
                    sWgt[row] = (s0 + row < EE) ? tanhf(pacc[mt][r] + bp2) : 0.f;
                }
            }
        }
    }
    __syncthreads();   // B4: sWgt visible

    // segment-reduced pos scatter: 12 threads = 3 comps x 4 spans of 16 rows
    if (tid < 12) {
        const int comp = tid % 3;
        const int r0 = (tid / 3) * 16;
        float accv = 0.f;
        int dprev = sDst[r0];
#pragma unroll
        for (int j = 0; j < 16; ++j) {
            const int r = r0 + j;
            int dcur = sDst[r];
            if (dcur != dprev) {
                if (accv != 0.f) unsafeAtomicAdd(&pos_acc[(size_t)dprev * 3 + comp], accv);
                accv = 0.f; dprev = dcur;
            }
            accv += sWgt[r] * ((const float*)&sC[r][128])[1 + comp];
        }
        if (accv != 0.f) unsafeAtomicAdd(&pos_acc[(size_t)dprev * 3 + comp], accv);
    }
}

// ---------------- update + fused pos output ----------------
__global__ __launch_bounds__(256) void update_kernel(
    const void* __restrict__ rawfeat, const void* __restrict__ rawpos,
    const u16* __restrict__ fU1, const u16* __restrict__ bu1,
    const u16* __restrict__ fU2, const u16* __restrict__ bu2,
    void* __restrict__ outp, const float* __restrict__ magg, const float* __restrict__ pacc,
    const int* __restrict__ flag)
{
    const int tid = threadIdx.x;
    const int lane = tid & 63;
    const int wv = tid >> 6;
    const int row0 = blockIdx.x * 64;
    const int isf = *flag;

    __shared__ u16 sA[64][136];   // features (bf16)
    __shared__ u16 sB[64][136];   // msg_acc -> hidden (reused)

    if (isf) {
        const float* fp = (const float*)rawfeat + (size_t)row0 * HH;
        for (int i = tid; i < 1024; i += 256) {
            int r = i >> 4, c = (i & 15) * 8;
            float4 v0 = *(const float4*)(fp + (size_t)r * HH + c);
            float4 v1 = *(const float4*)(fp + (size_t)r * HH + c + 4);
            uint4 o;
            o.x = (unsigned)f2bf(v0.x) | ((unsigned)f2bf(v0.y) << 16);
            o.y = (unsigned)f2bf(v0.z) | ((unsigned)f2bf(v0.w) << 16);
            o.z = (unsigned)f2bf(v1.x) | ((unsigned)f2bf(v1.y) << 16);
            o.w = (unsigned)f2bf(v1.z) | ((unsigned)f2bf(v1.w) << 16);
            *(uint4*)&sA[r][c] = o;
        }
    } else {
        const uint4* fp = (const uint4*)((const u16*)rawfeat + (size_t)row0 * HH);
        for (int i = tid; i < 1024; i += 256) {
            int r = i >> 4, c = i & 15;
            *(uint4*)&sA[r][c * 8] = fp[i];
        }
    }
    {
        const float4* am = (const float4*)(magg) + (size_t)row0 * 32;
        for (int i = tid; i < 2048; i += 256) {
            int r = i >> 5;
            float4 v = am[i];
            int c = (i & 31) * 4;
            sB[r][c + 0] = f2bf(v.x);
            sB[r][c + 1] = f2bf(v.y);
            sB[r][c + 2] = f2bf(v.z);
            sB[r][c + 3] = f2bf(v.w);
        }
    }
    __syncthreads();

    const int nt0 = wv * 2;
    const int mrow = lane & 15;
    const int kq = (lane >> 4) * 8;
    const int crow = (lane >> 4) * 4;
    const int ccol = lane & 15;

    f32x4 acc[4][2];
#pragma unroll
    for (int mt = 0; mt < 4; ++mt) {
        acc[mt][0] = (f32x4){0.f, 0.f, 0.f, 0.f};
        acc[mt][1] = (f32x4){0.f, 0.f, 0.f, 0.f};
    }
#pragma unroll
    for (int kt = 0; kt < 8; ++kt) {
        const u16* Xb = (kt < 4) ? &sA[0][0] : &sB[0][0];
        const int kk = (kt & 3) * 32 + kq;
        bf16x8 bw0 = *(const bf16x8*)(fU1 + (size_t)(((kt * 8 + nt0) * 64 + lane) * 8));
        bf16x8 bw1 = *(const bf16x8*)(fU1 + (size_t)(((kt * 8 + nt0 + 1) * 64 + lane) * 8));
#pragma unroll
        for (int mt = 0; mt < 4; ++mt) {
            bf16x8 a = *(const bf16x8*)(Xb + (mt * 16 + mrow) * 136 + kk);
            acc[mt][0] = MFMA(a, bw0, acc[mt][0]);
            acc[mt][1] = MFMA(a, bw1, acc[mt][1]);
        }
    }
    __syncthreads();

#pragma unroll
    for (int mt = 0; mt < 4; ++mt) {
#pragma unroll
        for (int n2 = 0; n2 < 2; ++n2) {
            const int col = (nt0 + n2) * 16 + ccol;
            const float bb = bf2f(bu1[col]);
#pragma unroll
            for (int r = 0; r < 4; ++r) {
                const int row = mt * 16 + crow + r;
                sB[row][col] = f2bf(silu_f(acc[mt][n2][r] + bb));
            }
        }
    }
    __syncthreads();

#pragma unroll
    for (int mt = 0; mt < 4; ++mt) {
        acc[mt][0] = (f32x4){0.f, 0.f, 0.f, 0.f};
        acc[mt][1] = (f32x4){0.f, 0.f, 0.f, 0.f};
    }
#pragma unroll
    for (int kt = 0; kt < 4; ++kt) {
        const int kk = kt * 32 + kq;
        bf16x8 bw0 = *(const bf16x8*)(fU2 + (size_t)(((kt * 8 + nt0) * 64 + lane) * 8));
        bf16x8 bw1 = *(const bf16x8*)(fU2 + (size_t)(((kt * 8 + nt0 + 1) * 64 + lane) * 8));
#pragma unroll
        for (int mt = 0; mt < 4; ++mt) {
            bf16x8 a = *(const bf16x8*)(&sB[0][0] + (mt * 16 + mrow) * 136 + kk);
            acc[mt][0] = MFMA(a, bw0, acc[mt][0]);
            acc[mt][1] = MFMA(a, bw1, acc[mt][1]);
        }
    }
#pragma unroll
    for (int mt = 0; mt < 4; ++mt) {
#pragma unroll
        for (int n2 = 0; n2 < 2; ++n2) {
            const int col = (nt0 + n2) * 16 + ccol;
            const float bb = bf2f(bu2[col]);
#pragma unroll
            for (int r = 0; r < 4; ++r) {
                const int row = mt * 16 + crow + r;
                const size_t idx = (size_t)(row0 + row) * HH + col;
                if (isf) {
                    float base = ((const float*)rawfeat)[idx];
                    ((float*)outp)[idx] = acc[mt][n2][r] + bb + base;
                } else {
                    float base = bf2f(sA[row][col]);
                    ((u16*)outp)[idx] = f2bf(acc[mt][n2][r] + bb + base);
                }
            }
        }
    }

    // fused positions output: 3 elems per node row (192 per block)
    if (tid < 192) {
        int i = row0 * 3 + tid;
        float x = pacc[i];
        if (isf) {
            float base = ((const float*)rawpos)[i];
            ((float*)outp)[5120000 + i] = base + 0.5f * x;
        } else {
            float base = bf2f(((const u16*)rawpos)[i]);
            ((u16*)outp)[5120000 + i] = f2bf(base + 0.5f * x);
        }
    }
}

extern "C" void kernel_launch(void* const* d_in, const int* in_sizes, int n_in,
                              void* d_out, int out_size, void* d_ws, size_t ws_size,
                              hipStream_t stream)
{
    // ws layout (bytes): identical to previous rounds
    float* ws_msg  = (float*)d_ws;
    float* ws_pos  = (float*)((char*)d_ws + 20480000);
    int*   cnt_up  = (int*)((char*)d_ws + 20960000);
    int*   cnt_dn  = (int*)((char*)d_ws + 21040000);
    int*   cur_up  = (int*)((char*)d_ws + 21120000);
    int*   cur_dn  = (int*)((char*)d_ws + 21200000);
    int*   bsum_up = (int*)((char*)d_ws + 21280000);
    int*   bsum_dn = (int*)((char*)d_ws + 21280400);
    int*   es_up   = (int*)((char*)d_ws + 21280800);
    int*   es_dn   = (int*)((char*)d_ws + 22080800);
    u16*   fbase   = (u16*)((char*)d_ws + 22880800);
    u16*   canon   = (u16*)((char*)d_ws + 23241248);
    int*   flag    = (int*)((char*)d_ws + 33804328);
    if (ws_size < 33804332ULL) return;

    u16* f_m1u = fbase;              // 32768 (K=256)
    u16* f_m2u = fbase + 32768;
    u16* f_p1u = fbase + 49152;      // fused W2@P1 frags (overwritten by gemm_fuse)
    u16* f_m1d = fbase + 65536;
    u16* f_m2d = fbase + 98304;
    u16* f_p1d = fbase + 114688;     // fused W2@P1 frags
    u16* f_u1  = fbase + 131072;
    u16* f_u2  = fbase + 163840;

    u16* cfeat  = canon;
    u16* cpos   = canon + 5120000;
    u16* cdgu   = canon + 5240000;
    u16* cdgd   = canon + 5260000;
    u16* cw1lu  = canon + 5280000;
    u16* cb1u   = canon + 5280128;
    u16* cb2u   = canon + 5280256;
    u16* cbp1u  = canon + 5280384;   // fused bias b2@P1+bp1 (overwritten by gemm_fuse)
    u16* cwp2u  = canon + 5280512;
    u16* cbp2u  = canon + 5280640;
    u16* cw1ld  = canon + 5280642;
    u16* cb1d   = canon + 5280770;
    u16* cb2d   = canon + 5280898;
    u16* cbp1d  = canon + 5281026;   // fused bias
    u16* cwp2d  = canon + 5281154;
    u16* cbp2d  = canon + 5281282;
    u16* cbu1   = canon + 5281284;
    u16* cbu2   = canon + 5281412;

    const int* ei_up = (const int*)d_in[2];
    const int* ei_dn = (const int*)d_in[3];

    // launch 0: DMA-zero ws_msg + ws_pos + cnt_up/cnt_dn (21.12 MB)
    hipMemsetAsync(d_ws, 0, 21120000, stream);

    // launch 1: detect dtype (flag only)
    detect_kernel<<<1, 256, 0, stream>>>((const u16*)d_in[0], flag);

    // launch 2: fused setup (vec8 canon | scalar tail | frags | edge counts)
    P18 cp;
    cp.p[0] = d_in[0];  cp.p[1] = d_in[1];  cp.p[2] = d_in[4];  cp.p[3] = d_in[5];
    cp.p[4] = d_in[6];  cp.p[5] = d_in[7];  cp.p[6] = d_in[9];  cp.p[7] = d_in[11];
    cp.p[8] = d_in[12]; cp.p[9] = d_in[13];
    cp.p[10] = d_in[14]; cp.p[11] = d_in[15]; cp.p[12] = d_in[17]; cp.p[13] = d_in[19];
    cp.p[14] = d_in[20]; cp.p[15] = d_in[21];
    cp.p[16] = d_in[23]; cp.p[17] = d_in[25];
    P8 wsf;
    wsf.w[0] = d_in[6];  wsf.w[1] = d_in[8];  wsf.w[2] = d_in[10]; wsf.w[3] = d_in[14];
    wsf.w[4] = d_in[16]; wsf.w[5] = d_in[18]; wsf.w[6] = d_in[22]; wsf.w[7] = d_in[24];
    setup_kernel<<<(SD2 + 255) / 256, 256, 0, stream>>>(cp, wsf, ei_up, ei_dn,
                                                        canon, fbase,
                                                        cnt_up, cnt_dn, flag);

    // launch 2b: W2@P1 fusion (overwrites f_p1 frags + cbp1 bias slots)
    gemm_fuse_kernel<<<128, 256, 0, stream>>>(d_in[8], d_in[10], d_in[9], d_in[11],
                                              d_in[16], d_in[18], d_in[17], d_in[19],
                                              f_p1u, f_p1d, cbp1u, cbp1d, flag);

    // launches 3-5: CSR scan + scatter
    SP sp;
    sp.cnt[0] = cnt_up; sp.cnt[1] = cnt_dn;
    sp.cur[0] = cur_up; sp.cur[1] = cur_dn;
    sp.bsum[0] = bsum_up; sp.bsum[1] = bsum_dn;
    scan1_kernel<<<2 * NBLK, 256, 0, stream>>>(sp);
    scan2_kernel<<<1, 256, 0, stream>>>(bsum_up, bsum_dn);
    scatter2_kernel<<<(2 * EE + 255) / 256, 256, 0, stream>>>(ei_up, ei_dn, cur_up, bsum_up,
                                                              cur_dn, bsum_dn, es_up, es_dn);

    // launch 6: edge kernel (r11 structure + pos2-via-MFMA)
    EP up, dn;
    up.eidx = ei_up; up.es = es_up; up.deg = cdgu;
    up.fW1 = f_m1u; up.fW2 = f_m2u;
    up.w1last = cw1lu; up.bias1 = cb1u; up.bias2 = cb2u;
    up.biasp1 = cbp1u; up.wp2 = cwp2u; up.biasp2 = cbp2u;
    dn.eidx = ei_dn; dn.es = es_dn; dn.deg = cdgd;
    dn.fW1 = f_m1d; dn.fW2 = f_m2d;
    dn.w1last = cw1ld; dn.bias1 = cb1d; dn.bias2 = cb2d;
    dn.biasp1 = cbp1d; dn.wp2 = cwp2d; dn.biasp2 = cbp2d;
    edge_kernel<<<NWG, 512, 0, stream>>>(cfeat, cpos, up, dn, ws_msg, ws_pos);

    // launch 7: update + positions out
    update_kernel<<<625, 256, 0, stream>>>(d_in[0], d_in[1], f_u1, cbu1, f_u2, cbu2,
                                           d_out, ws_msg, ws_pos, flag);
}

// Round 13
// 442.207 us; speedup vs baseline: 1.6559x; 1.0291x over previous
//
#include <hip/hip_runtime.h>
#include <hip/hip_bf16.h>

#define BB 2
#define NN 20000
#define HH 128
#define EE 200000
#define TR 64       // edge rows per block (64 -> 3 blocks/CU on LDS)
#define NEB 3125    // EE/64 exact
#define NBLK 79     // ceil(NN/256)
#define NWG (2 * BB * NEB)   // 12500

typedef unsigned short u16;
typedef __attribute__((ext_vector_type(4))) float f32x4;
typedef __bf16 bf16x8 __attribute__((ext_vector_type(8)));

#define MFMA(a, b, c) __builtin_amdgcn_mfma_f32_16x16x32_bf16((a), (b), (c), 0, 0, 0)

__device__ __forceinline__ float bf2f(u16 u) {
    union { unsigned int i; float f; } v; v.i = ((unsigned int)u) << 16; return v.f;
}
__device__ __forceinline__ u16 f2bf(float f) {
    union { __bf16 h; u16 u; } v; v.h = (__bf16)f; return v.u;
}
#if __has_builtin(__builtin_amdgcn_rcpf)
__device__ __forceinline__ float rcpf(float x) { return __builtin_amdgcn_rcpf(x); }
#else
__device__ __forceinline__ float rcpf(float x) { return 1.f / x; }
#endif
__device__ __forceinline__ float silu_f(float z) { return z * rcpf(1.f + __expf(-z)); }
// flag-routed load (setup kernels only): f32 raw or bf16 raw
__device__ __forceinline__ float ldv(const void* p, long i, int f) {
    return f ? ((const float*)p)[i] : bf2f(((const u16*)p)[i]);
}

// ---------------- launch 1: dtype detection (cnt zeroing via memset) ----------------
__global__ __launch_bounds__(256) void detect_kernel(const u16* __restrict__ f,
                                                     int* __restrict__ flag) {
    int tid = threadIdx.x;
    u16 v = f[tid * 2];
    int e = (v >> 7) & 0xFF;
    int ok = (e >= 101 && e <= 143) ? 1 : 0;
    __shared__ int c;
    if (tid == 0) c = 0;
    __syncthreads();
    atomicAdd(&c, ok);
    __syncthreads();
    if (tid == 0) *flag = (c < 200) ? 1 : 0;   // 1 => inputs are float32
}

// ---------------- launch 2: fused setup (canon | frags | edge counts) ----------------
// feat+pos canon region (5.24M elems) vectorized 8/thread; rest scalar.
#define C5TOT 5281540
#define FTOT 180224
#define SV 655000                 // vec8 threads: 640000 feat + 15000 pos
#define SCT 41540                 // scalar canon tail (C5TOT - 5240000)
#define SB2 (SV + SCT)
#define SC2 (SB2 + FTOT)
#define SD2 (SC2 + 2 * EE)
struct P18 { const void* p[18]; };
struct P8 { const void* w[8]; };

__global__ __launch_bounds__(256) void setup_kernel(
    P18 cp, P8 wf, const int* __restrict__ eu, const int* __restrict__ ed,
    u16* __restrict__ canon, u16* __restrict__ fbase,
    int* __restrict__ cnt_up, int* __restrict__ cnt_dn, const int* __restrict__ flag)
{
    long i = (long)blockIdx.x * 256 + threadIdx.x;
    const int isf = *flag;
    if (i < SV) {
        // vec8 canon: feat (threads < 640000) then pos
        long j = i * 8;
        if (isf) {
            const float* src = (j < 5120000)
                ? (const float*)cp.p[0] + j
                : (const float*)cp.p[1] + (j - 5120000);
            float4 v0 = *(const float4*)src;
            float4 v1 = *(const float4*)(src + 4);
            uint4 o;
            o.x = (unsigned)f2bf(v0.x) | ((unsigned)f2bf(v0.y) << 16);
            o.y = (unsigned)f2bf(v0.z) | ((unsigned)f2bf(v0.w) << 16);
            o.z = (unsigned)f2bf(v1.x) | ((unsigned)f2bf(v1.y) << 16);
            o.w = (unsigned)f2bf(v1.z) | ((unsigned)f2bf(v1.w) << 16);
            *(uint4*)&canon[j] = o;
        } else {
            const u16* src = (j < 5120000)
                ? (const u16*)cp.p[0] + j
                : (const u16*)cp.p[1] + (j - 5120000);
            *(uint4*)&canon[j] = *(const uint4*)src;
        }
        return;
    }
    long k = i - SV;
    if (k < SCT) {
        // scalar canon tail: deg/params region, j in [5240000, C5TOT)
        static const int off[19] = {
            0, 5120000, 5240000, 5260000, 5280000,
            5280128, 5280256, 5280384, 5280512, 5280640,
            5280642, 5280770, 5280898, 5281026, 5281154, 5281282,
            5281284, 5281412, 5281540 };
        static const int rsz[18] = {
            5120000, 120000, 20000, 20000,
            128, 128, 128, 128, 128, 1,
            128, 128, 128, 128, 128, 1,
            128, 128 };
        static const int soff[18] = {
            0, 0, 0, 0,
            32768, 0, 0, 0, 0, 0,
            32768, 0, 0, 0, 0, 0,
            0, 0 };
        int j = 5240000 + (int)k;
        int t = 0;
#pragma unroll 1
        while (j >= off[t + 1]) ++t;
        int kk = j - off[t];
        u16 v = 0;
        if (kk < rsz[t]) v = f2bf(ldv(cp.p[t], (long)soff[t] + kk, isf));
        canon[j] = v;
        return;
    }
    k -= SCT;
    if (k < FTOT) {
        static const int foff[9] = { 0, 32768, 49152, 65536, 98304, 114688,
                                     131072, 163840, 180224 };
        int j = (int)k;
        int t = 0;
#pragma unroll 1
        while (j >= foff[t + 1]) ++t;
        int m = j - foff[t];
        int jj = m & 7, lane = (m >> 3) & 63, nt = (m >> 9) & 7, kt = m >> 12;
        int kr = kt * 32 + ((lane >> 4) * 8) + jj;
        int n = nt * 16 + (lane & 15);
        fbase[j] = f2bf(ldv(wf.w[t], (long)kr * 128 + n, isf));
        return;
    }
    k -= FTOT;
    if (k < 2 * EE) {
        int e = (int)k;
        if (e < EE) atomicAdd(&cnt_up[eu[EE + e]], 1);
        else atomicAdd(&cnt_dn[ed[EE + e - EE]], 1);
    }
}

// ---------------- launch 2b: W2@P1 fusion precompute ----------------
__global__ __launch_bounds__(256) void gemm_fuse_kernel(
    const void* __restrict__ w2u, const void* __restrict__ p1u,
    const void* __restrict__ b2u, const void* __restrict__ bp1u,
    const void* __restrict__ w2d, const void* __restrict__ p1d,
    const void* __restrict__ b2d, const void* __restrict__ bp1d,
    u16* __restrict__ fragu, u16* __restrict__ fragd,
    u16* __restrict__ cbp1u, u16* __restrict__ cbp1d,
    const int* __restrict__ flag)
{
    const int dir = blockIdx.x >> 6;                 // 64 blocks per direction
    const int idx = (blockIdx.x & 63) * 256 + threadIdx.x;   // 0..16383
    const int k = idx >> 7, n = idx & 127;
    const int isf = *flag;
    const void* W2 = dir ? w2d : w2u;
    const void* P1 = dir ? p1d : p1u;
    float s = 0.f;
#pragma unroll 4
    for (int m = 0; m < 128; ++m)
        s += ldv(W2, (long)k * 128 + m, isf) * ldv(P1, (long)m * 128 + n, isf);
    u16* dst = dir ? fragd : fragu;
    dst[(((k >> 5) * 8 + (n >> 4)) * 64 + ((k >> 3) & 3) * 16 + (n & 15)) * 8 + (k & 7)] = f2bf(s);
    if (idx < 128) {
        const void* B2 = dir ? b2d : b2u;
        const void* BP1 = dir ? bp1d : bp1u;
        float t = 0.f;
#pragma unroll 4
        for (int m = 0; m < 128; ++m)
            t += ldv(B2, m, isf) * ldv(P1, (long)m * 128 + idx, isf);
        (dir ? cbp1d : cbp1u)[idx] = f2bf(t + ldv(BP1, idx, isf));
    }
}

// ---------------- CSR scans + scatter ----------------
struct SP { const int* cnt[2]; int* cur[2]; int* bsum[2]; };

__global__ __launch_bounds__(256) void scan1_kernel(SP p) {
    int half = blockIdx.x / NBLK;
    int b = blockIdx.x - half * NBLK;
    int t = threadIdx.x;
    int i = b * 256 + t;
    __shared__ int buf[256];
    int v = (i < NN) ? p.cnt[half][i] : 0;
    buf[t] = v;
    __syncthreads();
    for (int s = 1; s < 256; s <<= 1) {
        int x = (t >= s) ? buf[t - s] : 0;
        __syncthreads();
        buf[t] += x;
        __syncthreads();
    }
    if (i < NN) p.cur[half][i] = buf[t] - v;   // exclusive within block
    if (t == 255) p.bsum[half][b] = buf[255];
}

__global__ __launch_bounds__(256) void scan2_kernel(int* __restrict__ bu, int* __restrict__ bd) {
    __shared__ int buf[2][128];
    int half = threadIdx.x >> 7, t = threadIdx.x & 127;
    int* bs = half ? bd : bu;
    int v = (t < NBLK) ? bs[t] : 0;
    buf[half][t] = v;
    __syncthreads();
    for (int s = 1; s < 128; s <<= 1) {
        int x = (t >= s) ? buf[half][t - s] : 0;
        __syncthreads();
        buf[half][t] += x;
        __syncthreads();
    }
    if (t < NBLK) bs[t] = buf[half][t] - v;    // exclusive block offsets
}

__global__ void scatter2_kernel(const int* __restrict__ eu, const int* __restrict__ ed,
                                int* __restrict__ cu, const int* __restrict__ bu,
                                int* __restrict__ cd, const int* __restrict__ bd,
                                int* __restrict__ su, int* __restrict__ sd) {
    int e = blockIdx.x * 256 + threadIdx.x;
    if (e < EE) {
        int d = eu[EE + e];
        int p = atomicAdd(&cu[d], 1) + bu[d >> 8];
        su[p] = e;
    } else {
        e -= EE;
        if (e < EE) {
            int d = ed[EE + e];
            int p = atomicAdd(&cd[d], 1) + bd[d >> 8];
            sd[p] = e;
        }
    }
}

// ---------------- edge kernel: 64 rows/block, 3 blocks/CU, XCD-chunked ----------------
struct EP {
    const int* eidx; const int* es; const u16* deg;
    const u16* fW1; const u16* fW2;
    const u16* w1last; const u16* bias1; const u16* bias2;
    const u16* biasp1; const u16* wp2; const u16* biasp2;
};

// r11 structure (best measured edge: 259.5 us) + packed-bf16 msg atomics:
// msg accumulator is bf16; one global_atomic_pk_add_bf16 covers 2 cols ->
// atomic ops 16.6M -> 8.3M, WRITE 66.5 -> ~34 MB, RMW fetch halves.
__global__ __launch_bounds__(512, 6) void edge_kernel(
    const u16* __restrict__ feat, const u16* __restrict__ posit,   // canonical bf16
    EP up, EP dn,
    u16* __restrict__ msg_base, float* __restrict__ pos_base)
{
    const int tid = threadIdx.x;
    const int lane = tid & 63;
    const int wv = tid >> 6;
    const int bid0 = blockIdx.x;
    const int xcd = bid0 & 7;
    const int bid = (xcd < 4 ? xcd * 1563 : 4 * 1563 + (xcd - 4) * 1562) + (bid0 >> 3);
    const int half = bid / (BB * NEB);
    const int rem = bid - half * (BB * NEB);
    const int bb = rem / NEB;
    const int s0 = (rem - bb * NEB) * TR;
    const EP P = half ? dn : up;
    u16* msg_acc = msg_base + (size_t)bb * NN * HH;
    float* pos_acc = pos_base + (size_t)bb * NN * 3;

    __shared__ u16 sA[TR][136];
    __shared__ u16 sB[TR][136];
    __shared__ u16 sC[TR][136];
    __shared__ float sInv[TR];
    __shared__ float sWgt[TR];
    __shared__ int sDst[TR];

    const int wm = wv >> 2;        // 0..1 : 32-row half
    const int wn = wv & 3;         // 0..3 : column quarter
    const int rbase = wm * 32;
    const int mrow = lane & 15;
    const int kq = (lane >> 4) * 8;
    const int crow = (lane >> 4) * 4;
    const int ccol = lane & 15;

    // gather + meta (8 threads/row, 32B each; part 0 also does meta)
    {
        const int r = tid >> 3, part = tid & 7;
        int slot = s0 + r; if (slot >= EE) slot = EE - 1;
        int e = P.es[slot];
        int s = P.eidx[e];
        int d = P.eidx[EE + e];
        if (part == 0) {
            sDst[r] = d;
            sInv[r] = 1.f / fmaxf(bf2f(P.deg[d]), 1.f);
            const u16* ps = posit + ((size_t)bb * NN + s) * 3;
            const u16* pd = posit + ((size_t)bb * NN + d) * 3;
            float dx = bf2f(ps[0]) - bf2f(pd[0]);
            float dy = bf2f(ps[1]) - bf2f(pd[1]);
            float dz = bf2f(ps[2]) - bf2f(pd[2]);
            *(float4*)&sC[r][128] =
                make_float4(sqrtf(dx * dx + dy * dy + dz * dz), dx, dy, dz);
        }
        const uint4* fs = (const uint4*)(feat + ((size_t)bb * NN + s) * HH);
        const uint4* fd = (const uint4*)(feat + ((size_t)bb * NN + d) * HH);
        uint4* as = (uint4*)&sA[r][part * 16];
        uint4* ad = (uint4*)&sB[r][part * 16];
#pragma unroll
        for (int i = 0; i < 2; ++i) { as[i] = fs[part * 2 + i]; ad[i] = fd[part * 2 + i]; }
    }
    __syncthreads();   // B1

    // ----- msg layer 1 : [h_src | h_dst] @ W1[0:256]  (K=256, 2mt x 2nt/wave) -----
    f32x4 acc[2][2];
#pragma unroll
    for (int mt = 0; mt < 2; ++mt) {
        acc[mt][0] = (f32x4){0.f, 0.f, 0.f, 0.f};
        acc[mt][1] = (f32x4){0.f, 0.f, 0.f, 0.f};
    }
#pragma unroll
    for (int kt = 0; kt < 8; ++kt) {
        const u16* Xb = (kt < 4) ? &sA[0][0] : &sB[0][0];
        const int kk = (kt & 3) * 32 + kq;
        bf16x8 bw0 = *(const bf16x8*)(P.fW1 + (size_t)(((kt * 8 + wn * 2) * 64 + lane) * 8));
        bf16x8 bw1 = *(const bf16x8*)(P.fW1 + (size_t)(((kt * 8 + wn * 2 + 1) * 64 + lane) * 8));
#pragma unroll
        for (int mt = 0; mt < 2; ++mt) {
            bf16x8 a = *(const bf16x8*)(Xb + (rbase + mt * 16 + mrow) * 136 + kk);
            acc[mt][0] = MFMA(a, bw0, acc[mt][0]);
            acc[mt][1] = MFMA(a, bw1, acc[mt][1]);
        }
    }

    // L1 epilogue: + dist*W1[256] + b1, silu -> sC (fresh buffer, no barrier)
#pragma unroll
    for (int n2 = 0; n2 < 2; ++n2) {
        const int col = (wn * 2 + n2) * 16 + ccol;
        const float wl = bf2f(P.w1last[col]);
        const float bb1 = bf2f(P.bias1[col]);
#pragma unroll
        for (int mt = 0; mt < 2; ++mt) {
#pragma unroll
            for (int r = 0; r < 4; ++r) {
                const int row = rbase + mt * 16 + crow + r;
                const float dist = ((const float*)&sC[row][128])[0];
                float z = fmaf(dist, wl, acc[mt][n2][r]) + bb1;
                sC[row][col] = f2bf(silu_f(z));
            }
        }
    }
    __syncthreads();   // B2: L1 hidden visible; sA/sB reads done

    // ----- fused pass : sC @ [W2 | W2@P1]  (K=128, 16 n-tiles, 2mt x 4nt/wave) -----
    f32x4 facc[2][4];
#pragma unroll
    for (int mt = 0; mt < 2; ++mt)
#pragma unroll
        for (int j = 0; j < 4; ++j) facc[mt][j] = (f32x4){0.f, 0.f, 0.f, 0.f};
    const int nt0 = wn * 4;
#pragma unroll
    for (int kt = 0; kt < 4; ++kt) {
        const int kk = kt * 32 + kq;
        bf16x8 bw[4];
#pragma unroll
        for (int j = 0; j < 4; ++j) {
            const int nt = nt0 + j;
            const size_t off = (nt & 8)
                ? (size_t)(16384 + ((kt * 8 + (nt & 7)) * 64 + lane) * 8)
                : (size_t)(((kt * 8 + nt) * 64 + lane) * 8);
            bw[j] = *(const bf16x8*)(P.fW2 + off);
        }
#pragma unroll
        for (int mt = 0; mt < 2; ++mt) {
            bf16x8 a = *(const bf16x8*)(&sC[0][0] + (rbase + mt * 16 + mrow) * 136 + kk);
#pragma unroll
            for (int j = 0; j < 4; ++j) facc[mt][j] = MFMA(a, bw[j], facc[mt][j]);
        }
    }

    // fused epilogue: wn<2 -> messages (sA, +b2); wn>=2 -> pos-hidden (sB, silu+fused bias)
    if (wn < 2) {
#pragma unroll
        for (int j = 0; j < 4; ++j) {
            const int col = (nt0 + j) * 16 + ccol;
            const float b2v = bf2f(P.bias2[col]);
#pragma unroll
            for (int mt = 0; mt < 2; ++mt) {
#pragma unroll
                for (int r = 0; r < 4; ++r) {
                    const int row = rbase + mt * 16 + crow + r;
                    sA[row][col] = f2bf(facc[mt][j][r] + b2v);
                }
            }
        }
    } else {
#pragma unroll
        for (int j = 0; j < 4; ++j) {
            const int col = (nt0 - 8 + j) * 16 + ccol;
            const float fbv = bf2f(P.biasp1[col]);   // fused bias b2@P1 + bp1
#pragma unroll
            for (int mt = 0; mt < 2; ++mt) {
#pragma unroll
                for (int r = 0; r < 4; ++r) {
                    const int row = rbase + mt * 16 + crow + r;
                    sB[row][col] = f2bf(silu_f(facc[mt][j][r] + fbv));
                }
            }
        }
    }
    __syncthreads();   // B3: messages + pos-hidden visible

    // segment-reduced scatter of messages (rows sorted by dst):
    // 256 threads = 64 col-pairs x 4 row-spans of 16; packed bf16x2 atomics
    if (tid < 256) {
        const int cp2 = tid & 63;          // col pair: cols {2*cp2, 2*cp2+1}
        const int r0 = (tid >> 6) * 16;
        float v0[16], v1[16];
#pragma unroll
        for (int j = 0; j < 16; ++j) {
            unsigned w = *(const unsigned*)&sA[r0 + j][cp2 * 2];
            union { unsigned i; float f; } a, b;
            a.i = w << 16; b.i = w & 0xffff0000u;
            v0[j] = a.f; v1[j] = b.f;
        }
        float a0 = 0.f, a1 = 0.f;
        int dprev = sDst[r0];
        float invprev = sInv[r0];
#pragma unroll
        for (int j = 0; j < 16; ++j) {
            const int r = r0 + j;
            int dcur = sDst[r];
            if (dcur != dprev) {
                union { unsigned u; __hip_bfloat162 h; } pk;
                pk.u = (unsigned)f2bf(a0 * invprev) | ((unsigned)f2bf(a1 * invprev) << 16);
                unsafeAtomicAdd((__hip_bfloat162*)(msg_acc + (size_t)dprev * HH + cp2 * 2), pk.h);
                a0 = 0.f; a1 = 0.f; dprev = dcur; invprev = sInv[r];
            }
            if (s0 + r < EE) { a0 += v0[j]; a1 += v1[j]; }
        }
        union { unsigned u; __hip_bfloat162 h; } pk;
        pk.u = (unsigned)f2bf(a0 * invprev) | ((unsigned)f2bf(a1 * invprev) << 16);
        unsafeAtomicAdd((__hip_bfloat162*)(msg_acc + (size_t)dprev * HH + cp2 * 2), pk.h);
    }

    // ----- pos layer 2 : tanh(hidden @ p2 + bp2) -> sWgt (VALU dot, r11 form) -----
    {
        const int r = tid >> 2, q = tid & 3;   // 4 threads/row, 32 cols each
        if (r < TR) {
            const unsigned* t32 = (const unsigned*)&sB[r][q * 32];
            const unsigned* w32 = (const unsigned*)(P.wp2 + q * 32);
            float p = 0.f;
#pragma unroll
            for (int k = 0; k < 16; ++k) {
                unsigned a = t32[k], b = w32[k];
                union { unsigned i; float f; } al, ah, bl, bh;
                al.i = a << 16; ah.i = a & 0xffff0000u;
                bl.i = b << 16; bh.i = b & 0xffff0000u;
                p = fmaf(al.f, bl.f, p);
                p = fmaf(ah.f, bh.f, p);
            }
            p += __shfl_xor(p, 1);
            p += __shfl_xor(p, 2);
            if (q == 0)
                sWgt[r] = (s0 + r < EE) ? tanhf(p + bf2f(P.biasp2[0])) : 0.f;
        }
    }
    __syncthreads();   // B4: sWgt visible

    // segment-reduced pos scatter: 12 threads = 3 comps x 4 spans of 16 rows
    if (tid < 12) {
        const int comp = tid % 3;
        const int r0 = (tid / 3) * 16;
        float accv = 0.f;
        int dprev = sDst[r0];
#pragma unroll
        for (int j = 0; j < 16; ++j) {
            const int r = r0 + j;
            int dcur = sDst[r];
            if (dcur != dprev) {
                if (accv != 0.f) unsafeAtomicAdd(&pos_acc[(size_t)dprev * 3 + comp], accv);
                accv = 0.f; dprev = dcur;
            }
            accv += sWgt[r] * ((const float*)&sC[r][128])[1 + comp];
        }
        if (accv != 0.f) unsafeAtomicAdd(&pos_acc[(size_t)dprev * 3 + comp], accv);
    }
}

// ---------------- update + fused pos output ----------------
__global__ __launch_bounds__(256) void update_kernel(
    const void* __restrict__ rawfeat, const void* __restrict__ rawpos,
    const u16* __restrict__ fU1, const u16* __restrict__ bu1,
    const u16* __restrict__ fU2, const u16* __restrict__ bu2,
    void* __restrict__ outp, const u16* __restrict__ magg, const float* __restrict__ pacc,
    const int* __restrict__ flag)
{
    const int tid = threadIdx.x;
    const int lane = tid & 63;
    const int wv = tid >> 6;
    const int row0 = blockIdx.x * 64;
    const int isf = *flag;

    __shared__ u16 sA[64][136];   // features (bf16)
    __shared__ u16 sB[64][136];   // msg_acc -> hidden (reused)

    if (isf) {
        const float* fp = (const float*)rawfeat + (size_t)row0 * HH;
        for (int i = tid; i < 1024; i += 256) {
            int r = i >> 4, c = (i & 15) * 8;
            float4 v0 = *(const float4*)(fp + (size_t)r * HH + c);
            float4 v1 = *(const float4*)(fp + (size_t)r * HH + c + 4);
            uint4 o;
            o.x = (unsigned)f2bf(v0.x) | ((unsigned)f2bf(v0.y) << 16);
            o.y = (unsigned)f2bf(v0.z) | ((unsigned)f2bf(v0.w) << 16);
            o.z = (unsigned)f2bf(v1.x) | ((unsigned)f2bf(v1.y) << 16);
            o.w = (unsigned)f2bf(v1.z) | ((unsigned)f2bf(v1.w) << 16);
            *(uint4*)&sA[r][c] = o;
        }
    } else {
        const uint4* fp = (const uint4*)((const u16*)rawfeat + (size_t)row0 * HH);
        for (int i = tid; i < 1024; i += 256) {
            int r = i >> 4, c = i & 15;
            *(uint4*)&sA[r][c * 8] = fp[i];
        }
    }
    {
        // msg is already bf16: straight copy (10.2 MB total vs 20.5 f32)
        const uint4* am = (const uint4*)magg + (size_t)row0 * 16;
        for (int i = tid; i < 1024; i += 256) {
            int r = i >> 4, c = i & 15;
            *(uint4*)&sB[r][c * 8] = am[i];
        }
    }
    __syncthreads();

    const int nt0 = wv * 2;
    const int mrow = lane & 15;
    const int kq = (lane >> 4) * 8;
    const int crow = (lane >> 4) * 4;
    const int ccol = lane & 15;

    f32x4 acc[4][2];
#pragma unroll
    for (int mt = 0; mt < 4; ++mt) {
        acc[mt][0] = (f32x4){0.f, 0.f, 0.f, 0.f};
        acc[mt][1] = (f32x4){0.f, 0.f, 0.f, 0.f};
    }
#pragma unroll
    for (int kt = 0; kt < 8; ++kt) {
        const u16* Xb = (kt < 4) ? &sA[0][0] : &sB[0][0];
        const int kk = (kt & 3) * 32 + kq;
        bf16x8 bw0 = *(const bf16x8*)(fU1 + (size_t)(((kt * 8 + nt0) * 64 + lane) * 8));
        bf16x8 bw1 = *(const bf16x8*)(fU1 + (size_t)(((kt * 8 + nt0 + 1) * 64 + lane) * 8));
#pragma unroll
        for (int mt = 0; mt < 4; ++mt) {
            bf16x8 a = *(const bf16x8*)(Xb + (mt * 16 + mrow) * 136 + kk);
            acc[mt][0] = MFMA(a, bw0, acc[mt][0]);
            acc[mt][1] = MFMA(a, bw1, acc[mt][1]);
        }
    }
    __syncthreads();

#pragma unroll
    for (int mt = 0; mt < 4; ++mt) {
#pragma unroll
        for (int n2 = 0; n2 < 2; ++n2) {
            const int col = (nt0 + n2) * 16 + ccol;
            const float bb = bf2f(bu1[col]);
#pragma unroll
            for (int r = 0; r < 4; ++r) {
                const int row = mt * 16 + crow + r;
                sB[row][col] = f2bf(silu_f(acc[mt][n2][r] + bb));
            }
        }
    }
    __syncthreads();

#pragma unroll
    for (int mt = 0; mt < 4; ++mt) {
        acc[mt][0] = (f32x4){0.f, 0.f, 0.f, 0.f};
        acc[mt][1] = (f32x4){0.f, 0.f, 0.f, 0.f};
    }
#pragma unroll
    for (int kt = 0; kt < 4; ++kt) {
        const int kk = kt * 32 + kq;
        bf16x8 bw0 = *(const bf16x8*)(fU2 + (size_t)(((kt * 8 + nt0) * 64 + lane) * 8));
        bf16x8 bw1 = *(const bf16x8*)(fU2 + (size_t)(((kt * 8 + nt0 + 1) * 64 + lane) * 8));
#pragma unroll
        for (int mt = 0; mt < 4; ++mt) {
            bf16x8 a = *(const bf16x8*)(&sB[0][0] + (mt * 16 + mrow) * 136 + kk);
            acc[mt][0] = MFMA(a, bw0, acc[mt][0]);
            acc[mt][1] = MFMA(a, bw1, acc[mt][1]);
        }
    }
#pragma unroll
    for (int mt = 0; mt < 4; ++mt) {
#pragma unroll
        for (int n2 = 0; n2 < 2; ++n2) {
            const int col = (nt0 + n2) * 16 + ccol;
            const float bb = bf2f(bu2[col]);
#pragma unroll
            for (int r = 0; r < 4; ++r) {
                const int row = mt * 16 + crow + r;
                const size_t idx = (size_t)(row0 + row) * HH + col;
                if (isf) {
                    float base = ((const float*)rawfeat)[idx];
                    ((float*)outp)[idx] = acc[mt][n2][r] + bb + base;
                } else {
                    float base = bf2f(sA[row][col]);
                    ((u16*)outp)[idx] = f2bf(acc[mt][n2][r] + bb + base);
                }
            }
        }
    }

    // fused positions output: 3 elems per node row (192 per block)
    if (tid < 192) {
        int i = row0 * 3 + tid;
        float x = pacc[i];
        if (isf) {
            float base = ((const float*)rawpos)[i];
            ((float*)outp)[5120000 + i] = base + 0.5f * x;
        } else {
            float base = bf2f(((const u16*)rawpos)[i]);
            ((u16*)outp)[5120000 + i] = f2bf(base + 0.5f * x);
        }
    }
}

extern "C" void kernel_launch(void* const* d_in, const int* in_sizes, int n_in,
                              void* d_out, int out_size, void* d_ws, size_t ws_size,
                              hipStream_t stream)
{
    // ws layout (bytes): same offsets; ws_msg region holds bf16 messages
    // (10.24 MB used of 20.48).
    u16*   ws_msg  = (u16*)d_ws;
    float* ws_pos  = (float*)((char*)d_ws + 20480000);
    int*   cnt_up  = (int*)((char*)d_ws + 20960000);
    int*   cnt_dn  = (int*)((char*)d_ws + 21040000);
    int*   cur_up  = (int*)((char*)d_ws + 21120000);
    int*   cur_dn  = (int*)((char*)d_ws + 21200000);
    int*   bsum_up = (int*)((char*)d_ws + 21280000);
    int*   bsum_dn = (int*)((char*)d_ws + 21280400);
    int*   es_up   = (int*)((char*)d_ws + 21280800);
    int*   es_dn   = (int*)((char*)d_ws + 22080800);
    u16*   fbase   = (u16*)((char*)d_ws + 22880800);
    u16*   canon   = (u16*)((char*)d_ws + 23241248);
    int*   flag    = (int*)((char*)d_ws + 33804328);
    if (ws_size < 33804332ULL) return;

    u16* f_m1u = fbase;              // 32768 (K=256)
    u16* f_m2u = fbase + 32768;
    u16* f_p1u = fbase + 49152;      // fused W2@P1 frags (overwritten by gemm_fuse)
    u16* f_m1d = fbase + 65536;
    u16* f_m2d = fbase + 98304;
    u16* f_p1d = fbase + 114688;     // fused W2@P1 frags
    u16* f_u1  = fbase + 131072;
    u16* f_u2  = fbase + 163840;

    u16* cfeat  = canon;
    u16* cpos   = canon + 5120000;
    u16* cdgu   = canon + 5240000;
    u16* cdgd   = canon + 5260000;
    u16* cw1lu  = canon + 5280000;
    u16* cb1u   = canon + 5280128;
    u16* cb2u   = canon + 5280256;
    u16* cbp1u  = canon + 5280384;   // fused bias b2@P1+bp1 (overwritten by gemm_fuse)
    u16* cwp2u  = canon + 5280512;
    u16* cbp2u  = canon + 5280640;
    u16* cw1ld  = canon + 5280642;
    u16* cb1d   = canon + 5280770;
    u16* cb2d   = canon + 5280898;
    u16* cbp1d  = canon + 5281026;   // fused bias
    u16* cwp2d  = canon + 5281154;
    u16* cbp2d  = canon + 5281282;
    u16* cbu1   = canon + 5281284;
    u16* cbu2   = canon + 5281412;

    const int* ei_up = (const int*)d_in[2];
    const int* ei_dn = (const int*)d_in[3];

    // launch 0: DMA-zero ws_msg + ws_pos + cnt_up/cnt_dn (21.12 MB)
    hipMemsetAsync(d_ws, 0, 21120000, stream);

    // launch 1: detect dtype (flag only)
    detect_kernel<<<1, 256, 0, stream>>>((const u16*)d_in[0], flag);

    // launch 2: fused setup (vec8 canon | scalar tail | frags | edge counts)
    P18 cp;
    cp.p[0] = d_in[0];  cp.p[1] = d_in[1];  cp.p[2] = d_in[4];  cp.p[3] = d_in[5];
    cp.p[4] = d_in[6];  cp.p[5] = d_in[7];  cp.p[6] = d_in[9];  cp.p[7] = d_in[11];
    cp.p[8] = d_in[12]; cp.p[9] = d_in[13];
    cp.p[10] = d_in[14]; cp.p[11] = d_in[15]; cp.p[12] = d_in[17]; cp.p[13] = d_in[19];
    cp.p[14] = d_in[20]; cp.p[15] = d_in[21];
    cp.p[16] = d_in[23]; cp.p[17] = d_in[25];
    P8 wsf;
    wsf.w[0] = d_in[6];  wsf.w[1] = d_in[8];  wsf.w[2] = d_in[10]; wsf.w[3] = d_in[14];
    wsf.w[4] = d_in[16]; wsf.w[5] = d_in[18]; wsf.w[6] = d_in[22]; wsf.w[7] = d_in[24];
    setup_kernel<<<(SD2 + 255) / 256, 256, 0, stream>>>(cp, wsf, ei_up, ei_dn,
                                                        canon, fbase,
                                                        cnt_up, cnt_dn, flag);

    // launch 2b: W2@P1 fusion (overwrites f_p1 frags + cbp1 bias slots)
    gemm_fuse_kernel<<<128, 256, 0, stream>>>(d_in[8], d_in[10], d_in[9], d_in[11],
                                              d_in[16], d_in[18], d_in[17], d_in[19],
                                              f_p1u, f_p1d, cbp1u, cbp1d, flag);

    // launches 3-5: CSR scan + scatter
    SP sp;
    sp.cnt[0] = cnt_up; sp.cnt[1] = cnt_dn;
    sp.cur[0] = cur_up; sp.cur[1] = cur_dn;
    sp.bsum[0] = bsum_up; sp.bsum[1] = bsum_dn;
    scan1_kernel<<<2 * NBLK, 256, 0, stream>>>(sp);
    scan2_kernel<<<1, 256, 0, stream>>>(bsum_up, bsum_dn);
    scatter2_kernel<<<(2 * EE + 255) / 256, 256, 0, stream>>>(ei_up, ei_dn, cur_up, bsum_up,
                                                              cur_dn, bsum_dn, es_up, es_dn);

    // launch 6: edge kernel (r11 structure + packed-bf16 msg atomics)
    EP up, dn;
    up.eidx = ei_up; up.es = es_up; up.deg = cdgu;
    up.fW1 = f_m1u; up.fW2 = f_m2u;
    up.w1last = cw1lu; up.bias1 = cb1u; up.bias2 = cb2u;
    up.biasp1 = cbp1u; up.wp2 = cwp2u; up.biasp2 = cbp2u;
    dn.eidx = ei_dn; dn.es = es_dn; dn.deg = cdgd;
    dn.fW1 = f_m1d; dn.fW2 = f_m2d;
    dn.w1last = cw1ld; dn.bias1 = cb1d; dn.bias2 = cb2d;
    dn.biasp1 = cbp1d; dn.wp2 = cwp2d; dn.biasp2 = cbp2d;
    edge_kernel<<<NWG, 512, 0, stream>>>(cfeat, cpos, up, dn, ws_msg, ws_pos);

    // launch 7: update + positions out
    update_kernel<<<625, 256, 0, stream>>>(d_in[0], d_in[1], f_u1, cbu1, f_u2, cbu2,
                                           d_out, ws_msg, ws_pos, flag);
}